// Round 4
// baseline (656.085 us; speedup 1.0000x reference)
//
#include <hip/hip_runtime.h>
#include <hip/hip_bf16.h>
#include <math.h>

// Problem constants
#define IN_DIM   384
#define GNN_DIM  256
#define HEADS    4
#define DH       64
#define N_PATCH  8192
#define N_TILES  128
#define N_EDGES  1024
#define N_TOT    (N_PATCH + N_TILES)   // 8320
#define NTB      (N_TOT / 8)           // 1040 bytes per HTb row
#define NEB      (N_EDGES / 8)         // 128 bytes per HNb row
#define CCAP     800                   // phaseC member capacity
#define CCLAMP   768
#define ECAP     1032                  // phaseE edge capacity

// MEASUREMENT ROUND: every kernel takes a runtime `reps` arg and re-executes
// its pure body reps times. Outputs identical; per-kernel dur scales ~x reps
// so kernels with true T >= ~14us become visible in rocprof top-5.
#define REPS 3

typedef short  bf16x8 __attribute__((ext_vector_type(8)));
typedef float  f32x4  __attribute__((ext_vector_type(4)));

// ---------------------------------------------------------------------------
__device__ __forceinline__ float waveReduce(float v) {
    #pragma unroll
    for (int o = 32; o > 0; o >>= 1) v += __shfl_down(v, o, 64);
    return v;
}
__device__ __forceinline__ float bflo(unsigned u) { return __uint_as_float(u << 16); }
__device__ __forceinline__ float bfhi(unsigned u) { return __uint_as_float(u & 0xffff0000u); }
__device__ __forceinline__ unsigned packbf2(float a, float b) {
    __hip_bfloat16 b0 = __float2bfloat16(a), b1 = __float2bfloat16(b);
    unsigned short u0, u1;
    __builtin_memcpy(&u0, &b0, 2);
    __builtin_memcpy(&u1, &b1, 2);
    return (unsigned)u0 | ((unsigned)u1 << 16);
}

// ---------------------------------------------------------------------------
// Fused prep kernel (grid-partitioned), rep-wrapped.
// ---------------------------------------------------------------------------
__global__ __launch_bounds__(256) void prep1(
    const float* __restrict__ H,
    unsigned char* __restrict__ HTb, unsigned char* __restrict__ HNb,
    const float* __restrict__ W0, __hip_bfloat16* __restrict__ Wt0,
    const float* __restrict__ W1, __hip_bfloat16* __restrict__ Wt1,
    const float* __restrict__ x, const float* __restrict__ ro,
    __hip_bfloat16* __restrict__ Xb,
    const int* __restrict__ ro_ids, int* __restrict__ outrow, int reps)
{
    __shared__ unsigned char tb[32][33];
    __shared__ float tf[32][33];
    int b = blockIdx.x, tid = threadIdx.x;
    int tx = tid & 31, ty = tid >> 5;

    for (int rep = 0; rep < reps; ++rep) {
        if (b < 8320) {
            int n0 = (b % 260) * 32;
            int e0 = (b / 260) * 32;
            #pragma unroll
            for (int r = 0; r < 4; ++r) {
                int row = ty + r * 8;
                tb[row][tx] = (H[(size_t)(n0 + row) * N_EDGES + e0 + tx] > 0.f) ? 1 : 0;
            }
            __syncthreads();
            if (tid < 128) {
                int er = tid >> 2, g = tid & 3;
                unsigned v = 0;
                #pragma unroll
                for (int i = 0; i < 8; ++i) v |= (unsigned)tb[g * 8 + i][er] << i;
                HTb[(size_t)(e0 + er) * NTB + (n0 >> 3) + g] = (unsigned char)v;
            } else {
                int id = tid - 128;
                int nr = id >> 2, g = id & 3;
                unsigned v = 0;
                #pragma unroll
                for (int i = 0; i < 8; ++i) v |= (unsigned)tb[nr][g * 8 + i] << i;
                HNb[(size_t)(n0 + nr) * NEB + (e0 >> 3) + g] = (unsigned char)v;
            }
        } else if (b < 8480) {
            const float* W; __hip_bfloat16* Wt; int K, k0, n0;
            if (b < 8416) {
                int i = b - 8320; W = W0; Wt = Wt0; K = IN_DIM;
                k0 = (i % 12) * 32; n0 = (i / 12) * 32;
            } else {
                int i = b - 8416; W = W1; Wt = Wt1; K = GNN_DIM;
                k0 = (i % 8) * 32; n0 = (i / 8) * 32;
            }
            #pragma unroll
            for (int r = 0; r < 4; ++r)
                tf[ty + r * 8][tx] = W[(size_t)(k0 + ty + r * 8) * GNN_DIM + n0 + tx];
            __syncthreads();
            #pragma unroll
            for (int r = 0; r < 4; ++r)
                Wt[(size_t)(n0 + ty + r * 8) * K + k0 + tx] =
                    __float2bfloat16(tf[tx][ty + r * 8]);
        } else if (b < 9000) {
            int nb = (b - 8480) * 16;
            for (int r = 0; r < 16; ++r) {
                int n = nb + r;
                for (int k = tid; k < IN_DIM; k += 256) {
                    float v = (n < N_PATCH) ? x[(size_t)n * IN_DIM + k] : ro[k];
                    Xb[(size_t)n * IN_DIM + k] = __float2bfloat16(v);
                }
            }
        } else {
            if (tid < N_TILES) {
                int r = ro_ids[tid] - N_PATCH;
                if (r >= 0 && r < N_TILES) outrow[r] = tid;
            }
        }
        __syncthreads();
    }
}

// ---------------------------------------------------------------------------
// Phase A (MFMA), rep-wrapped.
// ---------------------------------------------------------------------------
__global__ __launch_bounds__(256) void phaseA_mfma(
    const __hip_bfloat16* __restrict__ Xb,
    const __hip_bfloat16* __restrict__ Wt,
    int K, int KP,
    const float* __restrict__ nemb,
    const int* __restrict__ node_type,
    const float* __restrict__ asrc, const float* __restrict__ adst,
    const float* __restrict__ ebias,
    float* __restrict__ hP, __hip_bfloat16* __restrict__ hPb,
    float* __restrict__ expL, float* __restrict__ sdst, int reps)
{
    __shared__ char smem[16 * 260 * 4];
    unsigned short* xs = (unsigned short*)smem;
    float* cs = (float*)smem;

    int tid = threadIdx.x;
    int n0 = blockIdx.x * 16;
    int wave = tid >> 6, lane = tid & 63;
    int lr16 = lane & 15, quad = lane >> 4;

    for (int rep = 0; rep < reps; ++rep) {
        {
            int lr = tid >> 4, lc = tid & 15;
            for (int c = lc * 8; c < K; c += 128)
                *(uint4*)&xs[lr * KP + c] = *(const uint4*)&Xb[(size_t)(n0 + lr) * K + c];
        }
        __syncthreads();

        f32x4 acc[4];
        #pragma unroll
        for (int ct = 0; ct < 4; ++ct)
            acc[ct] = (f32x4){0.f, 0.f, 0.f, 0.f};

        for (int kc = 0; kc < K; kc += 32) {
            bf16x8 a = *(const bf16x8*)&xs[lr16 * KP + kc + quad * 8];
            #pragma unroll
            for (int ct = 0; ct < 4; ++ct) {
                int col = wave * 64 + ct * 16 + lr16;
                bf16x8 b = *(const bf16x8*)&Wt[(size_t)col * K + kc + quad * 8];
                acc[ct] = __builtin_amdgcn_mfma_f32_16x16x32_bf16(a, b, acc[ct], 0, 0, 0);
            }
        }
        __syncthreads();

        #pragma unroll
        for (int ct = 0; ct < 4; ++ct)
            #pragma unroll
            for (int g = 0; g < 4; ++g)
                cs[(quad * 4 + g) * 260 + wave * 64 + ct * 16 + lr16] = acc[ct][g];
        __syncthreads();

        int j = tid, h = j >> 6, l2 = j & 63;
        float as = asrc[h * DH + l2];
        float ad = adst[h * DH + l2];
        float eb0 = ebias[0 * HEADS + h], eb1 = ebias[1 * HEADS + h], eb2 = ebias[2 * HEADS + h];
        for (int r = 0; r < 16; ++r) {
            int n = n0 + r;
            float hv = cs[r * 260 + j] + nemb[node_type[n] * GNN_DIM + j];
            hP[(size_t)n * GNN_DIM + j] = hv;
            hPb[(size_t)n * GNN_DIM + j] = __float2bfloat16(hv);
            float ss = waveReduce(hv * as);
            float sd = waveReduce(hv * ad);
            if (l2 == 0) {
                sdst[n * HEADS + h] = sd;
                float l0 = ss + eb0; l0 = l0 > 0.f ? l0 : 0.2f * l0;
                float l1 = ss + eb1; l1 = l1 > 0.f ? l1 : 0.2f * l1;
                float lc2 = ss + eb2; lc2 = lc2 > 0.f ? lc2 : 0.2f * lc2;
                expL[n * 12 + 0 * HEADS + h] = __expf(l0);
                expL[n * 12 + 1 * HEADS + h] = __expf(l1);
                expL[n * 12 + 2 * HEADS + h] = __expf(lc2);
            }
        }
        __syncthreads();
    }
}

// ---------------------------------------------------------------------------
// Phase C FUSED (R1 version), rep-wrapped.
// ---------------------------------------------------------------------------
__global__ __launch_bounds__(512) void phaseC_fused(
    const unsigned char* __restrict__ HTb,
    const int* __restrict__ edge_type,
    const float* __restrict__ expL,
    const __hip_bfloat16* __restrict__ hPb,
    const float* __restrict__ aedg,
    __hip_bfloat16* __restrict__ mb, float* __restrict__ sedg, int reps)
{
    int e = blockIdx.x, j = threadIdx.x;
    int lane = j & 63, wv = j >> 6;
    __shared__ __align__(16) int   noff[CCAP];
    __shared__ __align__(16) float wh[4][CCAP];
    __shared__ float Zs[4];
    __shared__ float comb[3][128][2];
    __shared__ int   wtot[8];
    __shared__ int   tailc[4];

    const unsigned* Hu = (const unsigned*)(HTb + (size_t)e * NTB);
    int te = edge_type[e];

    for (int rep = 0; rep < reps; ++rep) {
        unsigned u = (j < 256) ? Hu[j] : 0u;
        int cnt = __popc(u);
        int s = cnt;
        #pragma unroll
        for (int o = 1; o < 64; o <<= 1) {
            int v = __shfl_up(s, o, 64);
            if (lane >= o) s += v;
        }
        if (lane == 63) wtot[wv] = s;
        if (j < 4) tailc[j] = __popc(Hu[256 + j]);
        __syncthreads();

        int base = 0, mainTot = 0;
        #pragma unroll
        for (int w = 0; w < 8; ++w) {
            int t = wtot[w];
            if (w < wv) base += t;
            mainTot += t;
        }
        int cfull = mainTot + tailc[0] + tailc[1] + tailc[2] + tailc[3];
        int c = min(cfull, CCAP - 16);
        {
            int off = base + s - cnt;
            int nb = j << 5;
            while (u) {
                int i = __ffs(u) - 1; u &= u - 1;
                if (off < CCAP) noff[off] = (nb + i) << 9;
                ++off;
            }
            if (j < 4) {
                int tb = mainTot;
                for (int k = 0; k < j; ++k) tb += tailc[k];
                unsigned ut = Hu[256 + j];
                int nb2 = (256 + j) << 5;
                while (ut) {
                    int i = __ffs(ut) - 1; ut &= ut - 1;
                    if (tb < CCAP) noff[tb] = (nb2 + i) << 9;
                    ++tb;
                }
            }
        }
        __syncthreads();

        int cP = (c + 15) & ~15;
        for (int i = j; i < c; i += 512) {
            int n = noff[i] >> 9;
            float4 w = *(const float4*)&expL[n * 12 + te * 4];
            wh[0][i] = w.x; wh[1][i] = w.y; wh[2][i] = w.z; wh[3][i] = w.w;
        }
        if (j < 16) {
            int i = c + j;
            if (i < cP) { noff[i] = 0; wh[0][i] = wh[1][i] = wh[2][i] = wh[3][i] = 0.f; }
        }
        __syncthreads();

        if (j < 256) {
            float p = 0.f;
            for (int i = lane; i < c; i += 64) p += wh[wv][i];
            p = waveReduce(p);
            if (lane == 0) Zs[wv] = p;
        }
        __syncthreads();

        int q = j >> 7, p = j & 127, h2 = p >> 5;
        const char* hb = (const char*)hPb;
        int coff = p << 2;
        float al0 = 0.f, ah0 = 0.f, al1 = 0.f, ah1 = 0.f;
        for (int i = q * 4; i < cP; i += 16) {
            int4   n4 = *(const int4*)&noff[i];
            float4 w4 = *(const float4*)&wh[h2][i];
            unsigned u0 = *(const unsigned*)(hb + n4.x + coff);
            unsigned u1 = *(const unsigned*)(hb + n4.y + coff);
            unsigned u2 = *(const unsigned*)(hb + n4.z + coff);
            unsigned u3 = *(const unsigned*)(hb + n4.w + coff);
            al0 += w4.x * bflo(u0); ah0 += w4.x * bfhi(u0);
            al1 += w4.y * bflo(u1); ah1 += w4.y * bfhi(u1);
            al0 += w4.z * bflo(u2); ah0 += w4.z * bfhi(u2);
            al1 += w4.w * bflo(u3); ah1 += w4.w * bfhi(u3);
        }
        float s0 = al0 + al1, s1 = ah0 + ah1;
        if (q > 0) { comb[q - 1][p][0] = s0; comb[q - 1][p][1] = s1; }
        __syncthreads();
        if (q == 0) {
            s0 += comb[0][p][0] + comb[1][p][0] + comb[2][p][0];
            s1 += comb[0][p][1] + comb[1][p][1] + comb[2][p][1];
            float Zi = 1.f / Zs[h2];
            float mv0 = s0 * Zi, mv1 = s1 * Zi;
            ((unsigned*)mb)[e * 128 + p] = packbf2(mv0, mv1);
            int d0 = (p & 31) << 1;
            float se = mv0 * aedg[h2 * DH + d0] + mv1 * aedg[h2 * DH + d0 + 1];
            #pragma unroll
            for (int o = 16; o > 0; o >>= 1) se += __shfl_down(se, o, 32);
            if ((p & 31) == 0) sedg[e * HEADS + h2] = se;
        }
        __syncthreads();
    }
}

// ---------------------------------------------------------------------------
// Phase E (layer 0), rep-wrapped.
// ---------------------------------------------------------------------------
__global__ __launch_bounds__(256) void phaseE(
    const unsigned char* __restrict__ HNb,
    const float* __restrict__ sdstArr,
    const float* __restrict__ sedg,
    const __hip_bfloat16* __restrict__ mb,
    const float* __restrict__ hP,
    __hip_bfloat16* __restrict__ hOutb, int reps)
{
    int n = blockIdx.x, j = threadIdx.x;
    int lane = j & 63, wv = j >> 6;
    __shared__ int cnt;
    __shared__ __align__(16) int   eidx[ECAP];
    __shared__ __align__(16) float wh[4][ECAP];
    __shared__ float Zs[4];
    __shared__ float comb[128][2];
    __shared__ float sdv[4];

    for (int rep = 0; rep < reps; ++rep) {
        if (j < 4) sdv[j] = sdstArr[n * HEADS + j];
        if (j == 0) cnt = 0;
        __syncthreads();
        if (j < 32) {
            unsigned b = ((const unsigned*)(HNb + (size_t)n * NEB))[j];
            int eb = j << 5;
            while (b) {
                int i = __ffs(b) - 1; b &= b - 1;
                int p = atomicAdd(&cnt, 1);
                eidx[p] = (eb + i) << 9;
            }
        }
        __syncthreads();
        int c = cnt;
        int cP = (c + 7) & ~7;
        for (int i = j; i < c; i += 256) {
            int e = eidx[i] >> 9;
            float4 sg = *(const float4*)&sedg[e * 4];
            float l0 = sdv[0] + sg.x; l0 = l0 > 0.f ? l0 : 0.2f * l0;
            float l1 = sdv[1] + sg.y; l1 = l1 > 0.f ? l1 : 0.2f * l1;
            float l2 = sdv[2] + sg.z; l2 = l2 > 0.f ? l2 : 0.2f * l2;
            float l3 = sdv[3] + sg.w; l3 = l3 > 0.f ? l3 : 0.2f * l3;
            wh[0][i] = __expf(l0); wh[1][i] = __expf(l1);
            wh[2][i] = __expf(l2); wh[3][i] = __expf(l3);
        }
        if (j < 8) {
            int i = c + j;
            if (i < cP) { eidx[i] = 0; wh[0][i] = wh[1][i] = wh[2][i] = wh[3][i] = 0.f; }
        }
        __syncthreads();
        {
            float p = 0.f;
            for (int i = lane; i < c; i += 64) p += wh[wv][i];
            p = waveReduce(p);
            if (lane == 0) Zs[wv] = p;
        }
        __syncthreads();

        int par = j >> 7, p = j & 127, h2 = p >> 5;
        const char* mbb = (const char*)mb;
        int coff = p << 2;
        float a0 = 0.f, b0 = 0.f, a1 = 0.f, b1 = 0.f;
        for (int i = par * 4; i < cP; i += 8) {
            int4   e4 = *(const int4*)&eidx[i];
            float4 w4 = *(const float4*)&wh[h2][i];
            unsigned u0 = *(const unsigned*)(mbb + e4.x + coff);
            unsigned u1 = *(const unsigned*)(mbb + e4.y + coff);
            unsigned u2 = *(const unsigned*)(mbb + e4.z + coff);
            unsigned u3 = *(const unsigned*)(mbb + e4.w + coff);
            a0 += w4.x * bflo(u0); b0 += w4.x * bfhi(u0);
            a1 += w4.y * bflo(u1); b1 += w4.y * bfhi(u1);
            a0 += w4.z * bflo(u2); b0 += w4.z * bfhi(u2);
            a1 += w4.w * bflo(u3); b1 += w4.w * bfhi(u3);
        }
        if (par == 1) { comb[p][0] = a0 + a1; comb[p][1] = b0 + b1; }
        __syncthreads();
        if (par == 0) {
            float o0 = a0 + a1 + comb[p][0];
            float o1 = b0 + b1 + comb[p][1];
            float Zi = 1.f / Zs[h2];
            o0 *= Zi; o1 *= Zi;
            o0 = o0 > 0.f ? o0 : expm1f(o0);
            o1 = o1 > 0.f ? o1 : expm1f(o1);
            float2 hr = *(const float2*)&hP[(size_t)n * GNN_DIM + 2 * p];
            ((unsigned*)hOutb)[n * 128 + p] = packbf2(o0 + hr.x, o1 + hr.y);
        }
        __syncthreads();
    }
}

// ---------------------------------------------------------------------------
// Phase E last (layer 1) + fused LN, rep-wrapped.
// ---------------------------------------------------------------------------
__global__ __launch_bounds__(256) void phaseE_last(
    const unsigned char* __restrict__ HNb,
    const float* __restrict__ sdstArr,
    const float* __restrict__ sedg,
    const __hip_bfloat16* __restrict__ mb,
    const float* __restrict__ hP,
    const float* __restrict__ ng, const float* __restrict__ nbeta,
    const float* __restrict__ bg, const float* __restrict__ bbeta,
    const int* __restrict__ outrow,
    float* __restrict__ out, int reps)
{
    int n = blockIdx.x, j = threadIdx.x;
    int lane = j & 63, wv = j >> 6;
    __shared__ int cnt;
    __shared__ __align__(16) int   eidx[ECAP];
    __shared__ __align__(16) float wh[4][ECAP];
    __shared__ float Zs[4];
    __shared__ float comb[128][2];
    __shared__ float sdv[4];
    __shared__ float red[4];

    for (int rep = 0; rep < reps; ++rep) {
        if (j < 4) sdv[j] = sdstArr[n * HEADS + j];
        if (j == 0) cnt = 0;
        __syncthreads();
        if (j < 32) {
            unsigned b = ((const unsigned*)(HNb + (size_t)n * NEB))[j];
            int eb = j << 5;
            while (b) {
                int i = __ffs(b) - 1; b &= b - 1;
                int p = atomicAdd(&cnt, 1);
                eidx[p] = (eb + i) << 9;
            }
        }
        __syncthreads();
        int c = cnt;
        int cP = (c + 7) & ~7;
        for (int i = j; i < c; i += 256) {
            int e = eidx[i] >> 9;
            float4 sg = *(const float4*)&sedg[e * 4];
            float l0 = sdv[0] + sg.x; l0 = l0 > 0.f ? l0 : 0.2f * l0;
            float l1 = sdv[1] + sg.y; l1 = l1 > 0.f ? l1 : 0.2f * l1;
            float l2 = sdv[2] + sg.z; l2 = l2 > 0.f ? l2 : 0.2f * l2;
            float l3 = sdv[3] + sg.w; l3 = l3 > 0.f ? l3 : 0.2f * l3;
            wh[0][i] = __expf(l0); wh[1][i] = __expf(l1);
            wh[2][i] = __expf(l2); wh[3][i] = __expf(l3);
        }
        if (j < 8) {
            int i = c + j;
            if (i < cP) { eidx[i] = 0; wh[0][i] = wh[1][i] = wh[2][i] = wh[3][i] = 0.f; }
        }
        __syncthreads();
        {
            float p = 0.f;
            for (int i = lane; i < c; i += 64) p += wh[wv][i];
            p = waveReduce(p);
            if (lane == 0) Zs[wv] = p;
        }
        __syncthreads();

        int par = j >> 7, p = j & 127, h2 = p >> 5;
        const char* mbb = (const char*)mb;
        int coff = p << 2;
        float a0 = 0.f, b0 = 0.f, a1 = 0.f, b1 = 0.f;
        for (int i = par * 4; i < cP; i += 8) {
            int4   e4 = *(const int4*)&eidx[i];
            float4 w4 = *(const float4*)&wh[h2][i];
            unsigned u0 = *(const unsigned*)(mbb + e4.x + coff);
            unsigned u1 = *(const unsigned*)(mbb + e4.y + coff);
            unsigned u2 = *(const unsigned*)(mbb + e4.z + coff);
            unsigned u3 = *(const unsigned*)(mbb + e4.w + coff);
            a0 += w4.x * bflo(u0); b0 += w4.x * bfhi(u0);
            a1 += w4.y * bflo(u1); b1 += w4.y * bfhi(u1);
            a0 += w4.z * bflo(u2); b0 += w4.z * bfhi(u2);
            a1 += w4.w * bflo(u3); b1 += w4.w * bfhi(u3);
        }
        if (par == 1) { comb[p][0] = a0 + a1; comb[p][1] = b0 + b1; }
        __syncthreads();

        float r0 = 0.f, r1 = 0.f;
        if (par == 0) {
            float o0 = a0 + a1 + comb[p][0];
            float o1 = b0 + b1 + comb[p][1];
            float Zi = 1.f / Zs[h2];
            o0 *= Zi; o1 *= Zi;
            o0 = o0 > 0.f ? o0 : expm1f(o0);
            o1 = o1 > 0.f ? o1 : expm1f(o1);
            float2 hr = *(const float2*)&hP[(size_t)n * GNN_DIM + 2 * p];
            r0 = o0 + hr.x; r1 = o1 + hr.y;
        }

        float sm = waveReduce(r0 + r1);
        if (lane == 0) red[wv] = sm;
        __syncthreads();
        float mean = (red[0] + red[1] + red[2] + red[3]) * (1.f / GNN_DIM);
        __syncthreads();
        float d0 = r0 - mean, d1 = r1 - mean;
        float sv = (par == 0) ? (d0 * d0 + d1 * d1) : 0.f;
        sv = waveReduce(sv);
        if (lane == 0) red[wv] = sv;
        __syncthreads();
        float var = (red[0] + red[1] + red[2] + red[3]) * (1.f / GNN_DIM);
        if (par == 0) {
            const float* g; const float* bta; size_t outOff;
            if (n < N_PATCH) { g = ng; bta = nbeta; outOff = (size_t)n * GNN_DIM; }
            else {
                int qq = outrow[n - N_PATCH];
                g = bg; bta = bbeta;
                outOff = (size_t)(N_PATCH + qq) * GNN_DIM;
            }
            float is = rsqrtf(var + 1e-5f);
            float2 gv = *(const float2*)&g[2 * p];
            float2 bv = *(const float2*)&bta[2 * p];
            float2 ov; ov.x = d0 * is * gv.x + bv.x; ov.y = d1 * is * gv.y + bv.y;
            *(float2*)&out[outOff + 2 * p] = ov;
        }
        __syncthreads();
    }
}

// ---------------------------------------------------------------------------
extern "C" void kernel_launch(void* const* d_in, const int* in_sizes, int n_in,
                              void* d_out, int out_size, void* d_ws, size_t ws_size,
                              hipStream_t stream) {
    const float* x_nodes   = (const float*)d_in[0];
    const float* readout   = (const float*)d_in[1];
    const int*   node_type = (const int*)d_in[2];
    const int*   edge_type = (const int*)d_in[3];
    const float* Hmat      = (const float*)d_in[4];
    const int*   ro_ids    = (const int*)d_in[5];
    const float* W0        = (const float*)d_in[6];
    const float* W1        = (const float*)d_in[7];
    const float* node_emb  = (const float*)d_in[8];
    const float* a_src     = (const float*)d_in[9];
    const float* a_dst     = (const float*)d_in[10];
    const float* a_edge    = (const float*)d_in[11];
    const float* edge_bias = (const float*)d_in[12];
    const float* node_g    = (const float*)d_in[13];
    const float* node_b    = (const float*)d_in[14];
    const float* bag_g     = (const float*)d_in[15];
    const float* bag_b     = (const float*)d_in[16];

    char* ws = (char*)d_ws;
    size_t off = 0;
    unsigned char* HTb = (unsigned char*)(ws + off); off += (size_t)N_EDGES * NTB;
    unsigned char* HNb = (unsigned char*)(ws + off); off += (size_t)N_TOT * NEB;
    off = (off + 255) & ~(size_t)255;
    float* hP   = (float*)(ws + off); off += (size_t)N_TOT * GNN_DIM * 4;
    __hip_bfloat16* hPb = (__hip_bfloat16*)(ws + off); off += (size_t)N_TOT * GNN_DIM * 2;
    __hip_bfloat16* mb  = (__hip_bfloat16*)(ws + off); off += (size_t)N_EDGES * GNN_DIM * 2;
    __hip_bfloat16* Xb0 = (__hip_bfloat16*)(ws + off); off += (size_t)N_TOT * IN_DIM * 2;
    __hip_bfloat16* Wt0 = (__hip_bfloat16*)(ws + off); off += (size_t)GNN_DIM * IN_DIM * 2;
    __hip_bfloat16* Wt1 = (__hip_bfloat16*)(ws + off); off += (size_t)GNN_DIM * GNN_DIM * 2;
    float* expL = (float*)(ws + off); off += (size_t)N_TOT * 12 * 4;
    float* sdst = (float*)(ws + off); off += (size_t)N_TOT * HEADS * 4;
    float* sedg = (float*)(ws + off); off += (size_t)N_EDGES * HEADS * 4;
    int* outrow = (int*)(ws + off); off += N_TILES * 4;
    __hip_bfloat16* hXb = Xb0;

    prep1<<<9001, 256, 0, stream>>>(Hmat, HTb, HNb, W0, Wt0, W1, Wt1,
                                    x_nodes, readout, Xb0, ro_ids, outrow, REPS);

    phaseA_mfma<<<N_TOT / 16, 256, 0, stream>>>(Xb0, Wt0, IN_DIM, IN_DIM + 8,
                                      node_emb, node_type,
                                      a_src, a_dst, edge_bias,
                                      hP, hPb, expL, sdst, REPS);
    phaseC_fused<<<N_EDGES, 512, 0, stream>>>(HTb, edge_type, expL, hPb,
                                              a_edge, mb, sedg, REPS);
    phaseE<<<N_TOT, 256, 0, stream>>>(HNb, sdst, sedg, mb, hP, hXb, REPS);

    phaseA_mfma<<<N_TOT / 16, 256, 0, stream>>>(hXb, Wt1, GNN_DIM, GNN_DIM + 8,
                                      node_emb + 4 * GNN_DIM, node_type,
                                      a_src + HEADS * DH, a_dst + HEADS * DH,
                                      edge_bias + 12,
                                      hP, hPb, expL, sdst, REPS);
    phaseC_fused<<<N_EDGES, 512, 0, stream>>>(HTb, edge_type, expL, hPb,
                                              a_edge + HEADS * DH, mb, sedg, REPS);
    phaseE_last<<<N_TOT, 256, 0, stream>>>(HNb, sdst, sedg, mb, hP,
                                           node_g, node_b, bag_g, bag_b, outrow,
                                           (float*)d_out, REPS);
}

// Round 5
// 390.677 us; speedup vs baseline: 1.6794x; 1.6794x over previous
//
#include <hip/hip_runtime.h>
#include <hip/hip_bf16.h>
#include <math.h>

// Problem constants
#define IN_DIM   384
#define GNN_DIM  256
#define HEADS    4
#define DH       64
#define N_PATCH  8192
#define N_TILES  128
#define N_EDGES  1024
#define N_TOT    (N_PATCH + N_TILES)   // 8320
#define NTB      (N_TOT / 8)           // 1040 bytes per HTb row
#define NEB      (N_EDGES / 8)         // 128 bytes per HNb row
#define CCAP     800                   // phaseC member capacity

typedef short  bf16x8 __attribute__((ext_vector_type(8)));
typedef float  f32x4  __attribute__((ext_vector_type(4)));

// ---------------------------------------------------------------------------
__device__ __forceinline__ float waveReduce(float v) {
    #pragma unroll
    for (int o = 32; o > 0; o >>= 1) v += __shfl_down(v, o, 64);
    return v; // valid in lane 0 of each 64-wide wave
}
__device__ __forceinline__ float bflo(unsigned u) { return __uint_as_float(u << 16); }
__device__ __forceinline__ float bfhi(unsigned u) { return __uint_as_float(u & 0xffff0000u); }
__device__ __forceinline__ unsigned packbf2(float a, float b) {
    __hip_bfloat16 b0 = __float2bfloat16(a), b1 = __float2bfloat16(b);
    unsigned short u0, u1;
    __builtin_memcpy(&u0, &b0, 2);
    __builtin_memcpy(&u1, &b1, 2);
    return (unsigned)u0 | ((unsigned)u1 << 16);
}

// ---------------------------------------------------------------------------
// Fused prep kernel (grid-partitioned): unchanged from R1 (298.5us baseline).
// ---------------------------------------------------------------------------
__global__ __launch_bounds__(256) void prep1(
    const float* __restrict__ H,
    unsigned char* __restrict__ HTb, unsigned char* __restrict__ HNb,
    const float* __restrict__ W0, __hip_bfloat16* __restrict__ Wt0,
    const float* __restrict__ W1, __hip_bfloat16* __restrict__ Wt1,
    const float* __restrict__ x, const float* __restrict__ ro,
    __hip_bfloat16* __restrict__ Xb,
    const int* __restrict__ ro_ids, int* __restrict__ outrow)
{
    __shared__ unsigned char tb[32][33];
    __shared__ float tf[32][33];
    int b = blockIdx.x, tid = threadIdx.x;
    int tx = tid & 31, ty = tid >> 5;          // ty in 0..7

    if (b < 8320) {
        int n0 = (b % 260) * 32;
        int e0 = (b / 260) * 32;
        #pragma unroll
        for (int r = 0; r < 4; ++r) {
            int row = ty + r * 8;
            tb[row][tx] = (H[(size_t)(n0 + row) * N_EDGES + e0 + tx] > 0.f) ? 1 : 0;
        }
        __syncthreads();
        if (tid < 128) {            // HTb: 32 edges x 4 node-bytes
            int er = tid >> 2, g = tid & 3;
            unsigned v = 0;
            #pragma unroll
            for (int i = 0; i < 8; ++i) v |= (unsigned)tb[g * 8 + i][er] << i;
            HTb[(size_t)(e0 + er) * NTB + (n0 >> 3) + g] = (unsigned char)v;
        } else {                    // HNb: 32 nodes x 4 edge-bytes
            int id = tid - 128;
            int nr = id >> 2, g = id & 3;
            unsigned v = 0;
            #pragma unroll
            for (int i = 0; i < 8; ++i) v |= (unsigned)tb[nr][g * 8 + i] << i;
            HNb[(size_t)(n0 + nr) * NEB + (e0 >> 3) + g] = (unsigned char)v;
        }
    } else if (b < 8480) {
        const float* W; __hip_bfloat16* Wt; int K, k0, n0;
        if (b < 8416) {
            int i = b - 8320; W = W0; Wt = Wt0; K = IN_DIM;
            k0 = (i % 12) * 32; n0 = (i / 12) * 32;
        } else {
            int i = b - 8416; W = W1; Wt = Wt1; K = GNN_DIM;
            k0 = (i % 8) * 32; n0 = (i / 8) * 32;
        }
        #pragma unroll
        for (int r = 0; r < 4; ++r)
            tf[ty + r * 8][tx] = W[(size_t)(k0 + ty + r * 8) * GNN_DIM + n0 + tx];
        __syncthreads();
        #pragma unroll
        for (int r = 0; r < 4; ++r)
            Wt[(size_t)(n0 + ty + r * 8) * K + k0 + tx] =
                __float2bfloat16(tf[tx][ty + r * 8]);
    } else if (b < 9000) {
        int nb = (b - 8480) * 16;
        for (int r = 0; r < 16; ++r) {
            int n = nb + r;
            for (int k = tid; k < IN_DIM; k += 256) {
                float v = (n < N_PATCH) ? x[(size_t)n * IN_DIM + k] : ro[k];
                Xb[(size_t)n * IN_DIM + k] = __float2bfloat16(v);
            }
        }
    } else {
        if (tid < N_TILES) {
            int r = ro_ids[tid] - N_PATCH;
            if (r >= 0 && r < N_TILES) outrow[r] = tid;
        }
    }
}

// ---------------------------------------------------------------------------
// Phase A (MFMA): h = Xb @ Wt^T + nemb[node_type]; fused s_src/s_dst/expL.
// Unchanged from R1.
// ---------------------------------------------------------------------------
__global__ __launch_bounds__(256) void phaseA_mfma(
    const __hip_bfloat16* __restrict__ Xb,  // [N_TOT, K] bf16
    const __hip_bfloat16* __restrict__ Wt,  // [256, K] bf16
    int K, int KP,                          // KP = K+8 (LDS row stride)
    const float* __restrict__ nemb,
    const int* __restrict__ node_type,
    const float* __restrict__ asrc, const float* __restrict__ adst,
    const float* __restrict__ ebias,
    float* __restrict__ hP, __hip_bfloat16* __restrict__ hPb,
    float* __restrict__ expL, float* __restrict__ sdst)
{
    __shared__ char smem[16 * 260 * 4];     // 16.6 KB, union of xs / cs
    unsigned short* xs = (unsigned short*)smem;  // [16][KP] bf16 bits
    float* cs = (float*)smem;                    // [16][260] f32

    int tid = threadIdx.x;
    int n0 = blockIdx.x * 16;

    {
        int lr = tid >> 4, lc = tid & 15;
        for (int c = lc * 8; c < K; c += 128)
            *(uint4*)&xs[lr * KP + c] = *(const uint4*)&Xb[(size_t)(n0 + lr) * K + c];
    }
    __syncthreads();

    int wave = tid >> 6, lane = tid & 63;
    int lr16 = lane & 15, quad = lane >> 4;

    f32x4 acc[4];
    #pragma unroll
    for (int ct = 0; ct < 4; ++ct)
        acc[ct] = (f32x4){0.f, 0.f, 0.f, 0.f};

    for (int kc = 0; kc < K; kc += 32) {
        bf16x8 a = *(const bf16x8*)&xs[lr16 * KP + kc + quad * 8];
        #pragma unroll
        for (int ct = 0; ct < 4; ++ct) {
            int col = wave * 64 + ct * 16 + lr16;
            bf16x8 b = *(const bf16x8*)&Wt[(size_t)col * K + kc + quad * 8];
            acc[ct] = __builtin_amdgcn_mfma_f32_16x16x32_bf16(a, b, acc[ct], 0, 0, 0);
        }
    }
    __syncthreads();   // xs dead; reuse as cs

    #pragma unroll
    for (int ct = 0; ct < 4; ++ct)
        #pragma unroll
        for (int g = 0; g < 4; ++g)
            cs[(quad * 4 + g) * 260 + wave * 64 + ct * 16 + lr16] = acc[ct][g];
    __syncthreads();

    int j = tid, h = j >> 6, l2 = j & 63;
    float as = asrc[h * DH + l2];
    float ad = adst[h * DH + l2];
    float eb0 = ebias[0 * HEADS + h], eb1 = ebias[1 * HEADS + h], eb2 = ebias[2 * HEADS + h];
    for (int r = 0; r < 16; ++r) {
        int n = n0 + r;
        float hv = cs[r * 260 + j] + nemb[node_type[n] * GNN_DIM + j];
        hP[(size_t)n * GNN_DIM + j] = hv;
        hPb[(size_t)n * GNN_DIM + j] = __float2bfloat16(hv);
        float ss = waveReduce(hv * as);
        float sd = waveReduce(hv * ad);
        if (l2 == 0) {
            sdst[n * HEADS + h] = sd;
            float l0 = ss + eb0; l0 = l0 > 0.f ? l0 : 0.2f * l0;
            float l1 = ss + eb1; l1 = l1 > 0.f ? l1 : 0.2f * l1;
            float lc2 = ss + eb2; lc2 = lc2 > 0.f ? lc2 : 0.2f * lc2;
            expL[n * 12 + 0 * HEADS + h] = __expf(l0);
            expL[n * 12 + 1 * HEADS + h] = __expf(l1);
            expL[n * 12 + 2 * HEADS + h] = __expf(lc2);
        }
    }
}

// ---------------------------------------------------------------------------
// Phase C FUSED: unchanged from R1 (one block per edge, 512 threads).
// ---------------------------------------------------------------------------
__global__ __launch_bounds__(512) void phaseC_fused(
    const unsigned char* __restrict__ HTb,   // [E, N_TOT/8] bits
    const int* __restrict__ edge_type,
    const float* __restrict__ expL,          // [N,3,4]
    const __hip_bfloat16* __restrict__ hPb,  // [N,256] bf16
    const float* __restrict__ aedg,          // [4,64]
    __hip_bfloat16* __restrict__ mb, float* __restrict__ sedg)
{
    int e = blockIdx.x, j = threadIdx.x;
    int lane = j & 63, wv = j >> 6;
    __shared__ __align__(16) int   noff[CCAP];
    __shared__ __align__(16) float wh[4][CCAP];
    __shared__ float Zs[4];
    __shared__ float comb[3][128][2];
    __shared__ int   wtot[8];
    __shared__ int   tailc[4];

    const unsigned* Hu = (const unsigned*)(HTb + (size_t)e * NTB);
    int te = edge_type[e];

    unsigned u = (j < 256) ? Hu[j] : 0u;
    int cnt = __popc(u);
    int s = cnt;
    #pragma unroll
    for (int o = 1; o < 64; o <<= 1) {
        int v = __shfl_up(s, o, 64);
        if (lane >= o) s += v;
    }
    if (lane == 63) wtot[wv] = s;
    if (j < 4) tailc[j] = __popc(Hu[256 + j]);
    __syncthreads();

    int base = 0, mainTot = 0;
    #pragma unroll
    for (int w = 0; w < 8; ++w) {
        int t = wtot[w];
        if (w < wv) base += t;
        mainTot += t;
    }
    int cfull = mainTot + tailc[0] + tailc[1] + tailc[2] + tailc[3];
    int c = min(cfull, CCAP - 16);
    {
        int off = base + s - cnt;
        int nb = j << 5;
        while (u) {
            int i = __ffs(u) - 1; u &= u - 1;
            if (off < CCAP) noff[off] = (nb + i) << 9;
            ++off;
        }
        if (j < 4) {
            int tb = mainTot;
            for (int k = 0; k < j; ++k) tb += tailc[k];
            unsigned ut = Hu[256 + j];
            int nb2 = (256 + j) << 5;
            while (ut) {
                int i = __ffs(ut) - 1; ut &= ut - 1;
                if (tb < CCAP) noff[tb] = (nb2 + i) << 9;
                ++tb;
            }
        }
    }
    __syncthreads();

    int cP = (c + 15) & ~15;
    for (int i = j; i < c; i += 512) {
        int n = noff[i] >> 9;
        float4 w = *(const float4*)&expL[n * 12 + te * 4];
        wh[0][i] = w.x; wh[1][i] = w.y; wh[2][i] = w.z; wh[3][i] = w.w;
    }
    if (j < 16) {
        int i = c + j;
        if (i < cP) { noff[i] = 0; wh[0][i] = wh[1][i] = wh[2][i] = wh[3][i] = 0.f; }
    }
    __syncthreads();

    if (j < 256) {
        float p = 0.f;
        for (int i = lane; i < c; i += 64) p += wh[wv][i];
        p = waveReduce(p);
        if (lane == 0) Zs[wv] = p;
    }
    __syncthreads();

    int q = j >> 7, p = j & 127, h2 = p >> 5;
    const char* hb = (const char*)hPb;
    int coff = p << 2;
    float al0 = 0.f, ah0 = 0.f, al1 = 0.f, ah1 = 0.f;
    for (int i = q * 4; i < cP; i += 16) {
        int4   n4 = *(const int4*)&noff[i];
        float4 w4 = *(const float4*)&wh[h2][i];
        unsigned u0 = *(const unsigned*)(hb + n4.x + coff);
        unsigned u1 = *(const unsigned*)(hb + n4.y + coff);
        unsigned u2 = *(const unsigned*)(hb + n4.z + coff);
        unsigned u3 = *(const unsigned*)(hb + n4.w + coff);
        al0 += w4.x * bflo(u0); ah0 += w4.x * bfhi(u0);
        al1 += w4.y * bflo(u1); ah1 += w4.y * bfhi(u1);
        al0 += w4.z * bflo(u2); ah0 += w4.z * bfhi(u2);
        al1 += w4.w * bflo(u3); ah1 += w4.w * bfhi(u3);
    }
    float s0 = al0 + al1, s1 = ah0 + ah1;
    if (q > 0) { comb[q - 1][p][0] = s0; comb[q - 1][p][1] = s1; }
    __syncthreads();
    if (q == 0) {
        s0 += comb[0][p][0] + comb[1][p][0] + comb[2][p][0];
        s1 += comb[0][p][1] + comb[1][p][1] + comb[2][p][1];
        float Zi = 1.f / Zs[h2];
        float mv0 = s0 * Zi, mv1 = s1 * Zi;
        ((unsigned*)mb)[e * 128 + p] = packbf2(mv0, mv1);
        int d0 = (p & 31) << 1;
        float se = mv0 * aedg[h2 * DH + d0] + mv1 * aedg[h2 * DH + d0 + 1];
        #pragma unroll
        for (int o = 16; o > 0; o >>= 1) se += __shfl_down(se, o, 32);
        if ((p & 31) == 0) sedg[e * HEADS + h2] = se;
    }
}

// ---------------------------------------------------------------------------
// Phase E WAVE-PER-NODE (layer 0): 1 wave = 1 node, 4 nodes/block, zero
// block barriers, wave-scan compaction (no atomics), coalesced uint2 row
// loads, in-wave Z butterfly. Logic correctness-verified inside R2 mega.
// ---------------------------------------------------------------------------
__global__ __launch_bounds__(256) void phaseE_w(
    const unsigned char* __restrict__ HNb,   // [N, E/8] bits
    const float* __restrict__ sdstArr,       // [N,4]
    const float* __restrict__ sedg,          // [E,4]
    const __hip_bfloat16* __restrict__ mb,   // [E,256] bf16
    const float* __restrict__ hP,            // [N,256] residual
    __hip_bfloat16* __restrict__ hOutb)
{
    __shared__ __align__(16) char wsm[4 * 5120];   // 20.5 KB, per-wave slices
    int tid = threadIdx.x, wv = tid >> 6, lane = tid & 63;
    char* wbase = wsm + wv * 5120;
    int*   eidxW = (int*)wbase;            // [256]
    float* wh4W  = (float*)(wbase + 1024); // [256][4]
    int hsel = lane >> 4;
    int n = blockIdx.x * 4 + wv;

    const unsigned* Hw = (const unsigned*)(HNb + (size_t)n * NEB);
    float4 sdv = *(const float4*)&sdstArr[n * 4];
    float4 zac = {0.f, 0.f, 0.f, 0.f};
    float a0 = 0.f, a1 = 0.f, a2 = 0.f, a3 = 0.f;
    const char* mbb = (const char*)mb;

    for (int ch = 0; ch < 4; ++ch) {    // 256-edge chunks
        unsigned u = (lane < 8) ? Hw[ch * 8 + lane] : 0u;
        int cnt = __popc(u), s = cnt;
        #pragma unroll
        for (int o = 1; o < 64; o <<= 1) {
            int v = __shfl_up(s, o, 64);
            if (lane >= o) s += v;
        }
        int tot = __shfl(s, 63, 64);
        int off = s - cnt, eb = (ch * 8 + lane) * 32;
        while (u) { int i = __ffs(u) - 1; u &= u - 1; eidxW[off++] = eb + i; }
        for (int i = lane; i < tot; i += 64) {
            int e = eidxW[i];
            float4 sg = *(const float4*)&sedg[e * 4];
            float l0 = sdv.x + sg.x; l0 = l0 > 0.f ? l0 : 0.2f * l0;
            float l1 = sdv.y + sg.y; l1 = l1 > 0.f ? l1 : 0.2f * l1;
            float l2 = sdv.z + sg.z; l2 = l2 > 0.f ? l2 : 0.2f * l2;
            float l3 = sdv.w + sg.w; l3 = l3 > 0.f ? l3 : 0.2f * l3;
            float4 w4 = {__expf(l0), __expf(l1), __expf(l2), __expf(l3)};
            *(float4*)&wh4W[i * 4] = w4;
            zac.x += w4.x; zac.y += w4.y; zac.z += w4.z; zac.w += w4.w;
        }
        int i = 0;
        for (; i + 3 < tot; i += 4) {
            int e0 = eidxW[i], e1 = eidxW[i + 1], e2 = eidxW[i + 2], e3 = eidxW[i + 3];
            float w0 = wh4W[i * 4 + hsel],       w1 = wh4W[(i + 1) * 4 + hsel];
            float w2 = wh4W[(i + 2) * 4 + hsel], w3 = wh4W[(i + 3) * 4 + hsel];
            uint2 v0 = *(const uint2*)(mbb + (size_t)e0 * 512 + lane * 8);
            uint2 v1 = *(const uint2*)(mbb + (size_t)e1 * 512 + lane * 8);
            uint2 v2 = *(const uint2*)(mbb + (size_t)e2 * 512 + lane * 8);
            uint2 v3 = *(const uint2*)(mbb + (size_t)e3 * 512 + lane * 8);
            a0 += w0 * bflo(v0.x); a1 += w0 * bfhi(v0.x);
            a2 += w0 * bflo(v0.y); a3 += w0 * bfhi(v0.y);
            a0 += w1 * bflo(v1.x); a1 += w1 * bfhi(v1.x);
            a2 += w1 * bflo(v1.y); a3 += w1 * bfhi(v1.y);
            a0 += w2 * bflo(v2.x); a1 += w2 * bfhi(v2.x);
            a2 += w2 * bflo(v2.y); a3 += w2 * bfhi(v2.y);
            a0 += w3 * bflo(v3.x); a1 += w3 * bfhi(v3.x);
            a2 += w3 * bflo(v3.y); a3 += w3 * bfhi(v3.y);
        }
        for (; i < tot; ++i) {
            int e0 = eidxW[i];
            float w0 = wh4W[i * 4 + hsel];
            uint2 v0 = *(const uint2*)(mbb + (size_t)e0 * 512 + lane * 8);
            a0 += w0 * bflo(v0.x); a1 += w0 * bfhi(v0.x);
            a2 += w0 * bflo(v0.y); a3 += w0 * bfhi(v0.y);
        }
    }
    #pragma unroll
    for (int o = 32; o > 0; o >>= 1) {
        zac.x += __shfl_xor(zac.x, o, 64);
        zac.y += __shfl_xor(zac.y, o, 64);
        zac.z += __shfl_xor(zac.z, o, 64);
        zac.w += __shfl_xor(zac.w, o, 64);
    }
    float Zh = hsel == 0 ? zac.x : hsel == 1 ? zac.y : hsel == 2 ? zac.z : zac.w;
    float Zi = 1.f / Zh;
    float o0 = a0 * Zi, o1 = a1 * Zi, o2 = a2 * Zi, o3 = a3 * Zi;
    o0 = o0 > 0.f ? o0 : expm1f(o0);
    o1 = o1 > 0.f ? o1 : expm1f(o1);
    o2 = o2 > 0.f ? o2 : expm1f(o2);
    o3 = o3 > 0.f ? o3 : expm1f(o3);
    float4 hr = *(const float4*)&hP[(size_t)n * GNN_DIM + lane * 4];
    uint2 pv;
    pv.x = packbf2(o0 + hr.x, o1 + hr.y);
    pv.y = packbf2(o2 + hr.z, o3 + hr.w);
    *(uint2*)((char*)hOutb + (size_t)n * 512 + lane * 8) = pv;
}

// ---------------------------------------------------------------------------
// Phase E last WAVE-PER-NODE (layer 1): same gather + in-wave layernorm.
// ---------------------------------------------------------------------------
__global__ __launch_bounds__(256) void phaseE_last_w(
    const unsigned char* __restrict__ HNb,
    const float* __restrict__ sdstArr,
    const float* __restrict__ sedg,
    const __hip_bfloat16* __restrict__ mb,
    const float* __restrict__ hP,
    const float* __restrict__ ng, const float* __restrict__ nbeta,
    const float* __restrict__ bg, const float* __restrict__ bbeta,
    const int* __restrict__ outrow,
    float* __restrict__ out)
{
    __shared__ __align__(16) char wsm[4 * 5120];
    int tid = threadIdx.x, wv = tid >> 6, lane = tid & 63;
    char* wbase = wsm + wv * 5120;
    int*   eidxW = (int*)wbase;
    float* wh4W  = (float*)(wbase + 1024);
    int hsel = lane >> 4;
    int n = blockIdx.x * 4 + wv;

    const unsigned* Hw = (const unsigned*)(HNb + (size_t)n * NEB);
    float4 sdv = *(const float4*)&sdstArr[n * 4];
    float4 zac = {0.f, 0.f, 0.f, 0.f};
    float a0 = 0.f, a1 = 0.f, a2 = 0.f, a3 = 0.f;
    const char* mbb = (const char*)mb;

    for (int ch = 0; ch < 4; ++ch) {
        unsigned u = (lane < 8) ? Hw[ch * 8 + lane] : 0u;
        int cnt = __popc(u), s = cnt;
        #pragma unroll
        for (int o = 1; o < 64; o <<= 1) {
            int v = __shfl_up(s, o, 64);
            if (lane >= o) s += v;
        }
        int tot = __shfl(s, 63, 64);
        int off = s - cnt, eb = (ch * 8 + lane) * 32;
        while (u) { int i = __ffs(u) - 1; u &= u - 1; eidxW[off++] = eb + i; }
        for (int i = lane; i < tot; i += 64) {
            int e = eidxW[i];
            float4 sg = *(const float4*)&sedg[e * 4];
            float l0 = sdv.x + sg.x; l0 = l0 > 0.f ? l0 : 0.2f * l0;
            float l1 = sdv.y + sg.y; l1 = l1 > 0.f ? l1 : 0.2f * l1;
            float l2 = sdv.z + sg.z; l2 = l2 > 0.f ? l2 : 0.2f * l2;
            float l3 = sdv.w + sg.w; l3 = l3 > 0.f ? l3 : 0.2f * l3;
            float4 w4 = {__expf(l0), __expf(l1), __expf(l2), __expf(l3)};
            *(float4*)&wh4W[i * 4] = w4;
            zac.x += w4.x; zac.y += w4.y; zac.z += w4.z; zac.w += w4.w;
        }
        int i = 0;
        for (; i + 3 < tot; i += 4) {
            int e0 = eidxW[i], e1 = eidxW[i + 1], e2 = eidxW[i + 2], e3 = eidxW[i + 3];
            float w0 = wh4W[i * 4 + hsel],       w1 = wh4W[(i + 1) * 4 + hsel];
            float w2 = wh4W[(i + 2) * 4 + hsel], w3 = wh4W[(i + 3) * 4 + hsel];
            uint2 v0 = *(const uint2*)(mbb + (size_t)e0 * 512 + lane * 8);
            uint2 v1 = *(const uint2*)(mbb + (size_t)e1 * 512 + lane * 8);
            uint2 v2 = *(const uint2*)(mbb + (size_t)e2 * 512 + lane * 8);
            uint2 v3 = *(const uint2*)(mbb + (size_t)e3 * 512 + lane * 8);
            a0 += w0 * bflo(v0.x); a1 += w0 * bfhi(v0.x);
            a2 += w0 * bflo(v0.y); a3 += w0 * bfhi(v0.y);
            a0 += w1 * bflo(v1.x); a1 += w1 * bfhi(v1.x);
            a2 += w1 * bflo(v1.y); a3 += w1 * bfhi(v1.y);
            a0 += w2 * bflo(v2.x); a1 += w2 * bfhi(v2.x);
            a2 += w2 * bflo(v2.y); a3 += w2 * bfhi(v2.y);
            a0 += w3 * bflo(v3.x); a1 += w3 * bfhi(v3.x);
            a2 += w3 * bflo(v3.y); a3 += w3 * bfhi(v3.y);
        }
        for (; i < tot; ++i) {
            int e0 = eidxW[i];
            float w0 = wh4W[i * 4 + hsel];
            uint2 v0 = *(const uint2*)(mbb + (size_t)e0 * 512 + lane * 8);
            a0 += w0 * bflo(v0.x); a1 += w0 * bfhi(v0.x);
            a2 += w0 * bflo(v0.y); a3 += w0 * bfhi(v0.y);
        }
    }
    #pragma unroll
    for (int o = 32; o > 0; o >>= 1) {
        zac.x += __shfl_xor(zac.x, o, 64);
        zac.y += __shfl_xor(zac.y, o, 64);
        zac.z += __shfl_xor(zac.z, o, 64);
        zac.w += __shfl_xor(zac.w, o, 64);
    }
    float Zh = hsel == 0 ? zac.x : hsel == 1 ? zac.y : hsel == 2 ? zac.z : zac.w;
    float Zi = 1.f / Zh;
    float o0 = a0 * Zi, o1 = a1 * Zi, o2 = a2 * Zi, o3 = a3 * Zi;
    o0 = o0 > 0.f ? o0 : expm1f(o0);
    o1 = o1 > 0.f ? o1 : expm1f(o1);
    o2 = o2 > 0.f ? o2 : expm1f(o2);
    o3 = o3 > 0.f ? o3 : expm1f(o3);
    float4 hr = *(const float4*)&hP[(size_t)n * GNN_DIM + lane * 4];
    float r0 = o0 + hr.x, r1 = o1 + hr.y, r2 = o2 + hr.z, r3 = o3 + hr.w;

    // in-wave layernorm over 256 cols
    float sm = r0 + r1 + r2 + r3;
    #pragma unroll
    for (int o = 32; o > 0; o >>= 1) sm += __shfl_xor(sm, o, 64);
    float mean = sm * (1.f / GNN_DIM);
    float d0 = r0 - mean, d1 = r1 - mean, d2 = r2 - mean, d3 = r3 - mean;
    float sv = d0 * d0 + d1 * d1 + d2 * d2 + d3 * d3;
    #pragma unroll
    for (int o = 32; o > 0; o >>= 1) sv += __shfl_xor(sv, o, 64);
    float var = sv * (1.f / GNN_DIM);
    float is = rsqrtf(var + 1e-5f);
    const float* g; const float* bta; size_t outOff;
    if (n < N_PATCH) { g = ng; bta = nbeta; outOff = (size_t)n * GNN_DIM; }
    else {
        int qq = outrow[n - N_PATCH];
        g = bg; bta = bbeta;
        outOff = (size_t)(N_PATCH + qq) * GNN_DIM;
    }
    float4 gv = *(const float4*)&g[lane * 4];
    float4 bv = *(const float4*)&bta[lane * 4];
    float4 ov;
    ov.x = d0 * is * gv.x + bv.x;
    ov.y = d1 * is * gv.y + bv.y;
    ov.z = d2 * is * gv.z + bv.z;
    ov.w = d3 * is * gv.w + bv.w;
    *(float4*)&out[outOff + lane * 4] = ov;
}

// ---------------------------------------------------------------------------
extern "C" void kernel_launch(void* const* d_in, const int* in_sizes, int n_in,
                              void* d_out, int out_size, void* d_ws, size_t ws_size,
                              hipStream_t stream) {
    const float* x_nodes   = (const float*)d_in[0];
    const float* readout   = (const float*)d_in[1];
    const int*   node_type = (const int*)d_in[2];
    const int*   edge_type = (const int*)d_in[3];
    const float* Hmat      = (const float*)d_in[4];
    const int*   ro_ids    = (const int*)d_in[5];
    const float* W0        = (const float*)d_in[6];
    const float* W1        = (const float*)d_in[7];
    const float* node_emb  = (const float*)d_in[8];
    const float* a_src     = (const float*)d_in[9];
    const float* a_dst     = (const float*)d_in[10];
    const float* a_edge    = (const float*)d_in[11];
    const float* edge_bias = (const float*)d_in[12];
    const float* node_g    = (const float*)d_in[13];
    const float* node_b    = (const float*)d_in[14];
    const float* bag_g     = (const float*)d_in[15];
    const float* bag_b     = (const float*)d_in[16];

    // Workspace layout (~22.7 MB)
    char* ws = (char*)d_ws;
    size_t off = 0;
    unsigned char* HTb = (unsigned char*)(ws + off); off += (size_t)N_EDGES * NTB;
    unsigned char* HNb = (unsigned char*)(ws + off); off += (size_t)N_TOT * NEB;
    off = (off + 255) & ~(size_t)255;
    float* hP   = (float*)(ws + off); off += (size_t)N_TOT * GNN_DIM * 4;
    __hip_bfloat16* hPb = (__hip_bfloat16*)(ws + off); off += (size_t)N_TOT * GNN_DIM * 2;
    __hip_bfloat16* mb  = (__hip_bfloat16*)(ws + off); off += (size_t)N_EDGES * GNN_DIM * 2;
    __hip_bfloat16* Xb0 = (__hip_bfloat16*)(ws + off); off += (size_t)N_TOT * IN_DIM * 2;
    __hip_bfloat16* Wt0 = (__hip_bfloat16*)(ws + off); off += (size_t)GNN_DIM * IN_DIM * 2;
    __hip_bfloat16* Wt1 = (__hip_bfloat16*)(ws + off); off += (size_t)GNN_DIM * GNN_DIM * 2;
    float* expL = (float*)(ws + off); off += (size_t)N_TOT * 12 * 4;
    float* sdst = (float*)(ws + off); off += (size_t)N_TOT * HEADS * 4;
    float* sedg = (float*)(ws + off); off += (size_t)N_EDGES * HEADS * 4;
    int* outrow = (int*)(ws + off); off += N_TILES * 4;
    __hip_bfloat16* hXb = Xb0;               // alias (Xb0 dead after layer-0 phaseA)

    // ----- fused prep -----
    prep1<<<9001, 256, 0, stream>>>(Hmat, HTb, HNb, W0, Wt0, W1, Wt1,
                                    x_nodes, readout, Xb0, ro_ids, outrow);

    // ----- layer 0 -----
    phaseA_mfma<<<N_TOT / 16, 256, 0, stream>>>(Xb0, Wt0, IN_DIM, IN_DIM + 8,
                                      node_emb, node_type,
                                      a_src, a_dst, edge_bias,
                                      hP, hPb, expL, sdst);
    phaseC_fused<<<N_EDGES, 512, 0, stream>>>(HTb, edge_type, expL, hPb,
                                              a_edge, mb, sedg);
    phaseE_w<<<N_TOT / 4, 256, 0, stream>>>(HNb, sdst, sedg, mb, hP, hXb);

    // ----- layer 1 -----
    phaseA_mfma<<<N_TOT / 16, 256, 0, stream>>>(hXb, Wt1, GNN_DIM, GNN_DIM + 8,
                                      node_emb + 4 * GNN_DIM, node_type,
                                      a_src + HEADS * DH, a_dst + HEADS * DH,
                                      edge_bias + 12,
                                      hP, hPb, expL, sdst);
    phaseC_fused<<<N_EDGES, 512, 0, stream>>>(HTb, edge_type, expL, hPb,
                                              a_edge + HEADS * DH, mb, sedg);
    phaseE_last_w<<<N_TOT / 4, 256, 0, stream>>>(HNb, sdst, sedg, mb, hP,
                                           node_g, node_b, bag_g, bag_b, outrow,
                                           (float*)d_out);
}

// Round 6
// 329.147 us; speedup vs baseline: 1.9933x; 1.1869x over previous
//
#include <hip/hip_runtime.h>
#include <hip/hip_bf16.h>
#include <math.h>

// Problem constants
#define IN_DIM   384
#define GNN_DIM  256
#define HEADS    4
#define DH       64
#define N_PATCH  8192
#define N_TILES  128
#define N_EDGES  1024
#define N_TOT    (N_PATCH + N_TILES)   // 8320
#define NTB      (N_TOT / 8)           // 1040 bytes per HTb row
#define NEB      (N_EDGES / 8)         // 128 bytes per HNb row
#define CCAP     800                   // phaseC member capacity
#define ECAP     1032                  // phaseE edge capacity

typedef short  bf16x8 __attribute__((ext_vector_type(8)));
typedef float  f32x4  __attribute__((ext_vector_type(4)));

// ---------------------------------------------------------------------------
__device__ __forceinline__ float waveReduce(float v) {
    #pragma unroll
    for (int o = 32; o > 0; o >>= 1) v += __shfl_down(v, o, 64);
    return v; // valid in lane 0 of each 64-wide wave
}
__device__ __forceinline__ float bflo(unsigned u) { return __uint_as_float(u << 16); }
__device__ __forceinline__ float bfhi(unsigned u) { return __uint_as_float(u & 0xffff0000u); }
__device__ __forceinline__ unsigned packbf2(float a, float b) {
    __hip_bfloat16 b0 = __float2bfloat16(a), b1 = __float2bfloat16(b);
    unsigned short u0, u1;
    __builtin_memcpy(&u0, &b0, 2);
    __builtin_memcpy(&u1, &b1, 2);
    return (unsigned)u0 | ((unsigned)u1 << 16);
}

// ---------------------------------------------------------------------------
// Fused prep kernel (grid-partitioned): unchanged from R1 (298.5us baseline).
// ---------------------------------------------------------------------------
__global__ __launch_bounds__(256) void prep1(
    const float* __restrict__ H,
    unsigned char* __restrict__ HTb, unsigned char* __restrict__ HNb,
    const float* __restrict__ W0, __hip_bfloat16* __restrict__ Wt0,
    const float* __restrict__ W1, __hip_bfloat16* __restrict__ Wt1,
    const float* __restrict__ x, const float* __restrict__ ro,
    __hip_bfloat16* __restrict__ Xb,
    const int* __restrict__ ro_ids, int* __restrict__ outrow)
{
    __shared__ unsigned char tb[32][33];
    __shared__ float tf[32][33];
    int b = blockIdx.x, tid = threadIdx.x;
    int tx = tid & 31, ty = tid >> 5;          // ty in 0..7

    if (b < 8320) {
        int n0 = (b % 260) * 32;
        int e0 = (b / 260) * 32;
        #pragma unroll
        for (int r = 0; r < 4; ++r) {
            int row = ty + r * 8;
            tb[row][tx] = (H[(size_t)(n0 + row) * N_EDGES + e0 + tx] > 0.f) ? 1 : 0;
        }
        __syncthreads();
        if (tid < 128) {            // HTb: 32 edges x 4 node-bytes
            int er = tid >> 2, g = tid & 3;
            unsigned v = 0;
            #pragma unroll
            for (int i = 0; i < 8; ++i) v |= (unsigned)tb[g * 8 + i][er] << i;
            HTb[(size_t)(e0 + er) * NTB + (n0 >> 3) + g] = (unsigned char)v;
        } else {                    // HNb: 32 nodes x 4 edge-bytes
            int id = tid - 128;
            int nr = id >> 2, g = id & 3;
            unsigned v = 0;
            #pragma unroll
            for (int i = 0; i < 8; ++i) v |= (unsigned)tb[nr][g * 8 + i] << i;
            HNb[(size_t)(n0 + nr) * NEB + (e0 >> 3) + g] = (unsigned char)v;
        }
    } else if (b < 8480) {
        const float* W; __hip_bfloat16* Wt; int K, k0, n0;
        if (b < 8416) {
            int i = b - 8320; W = W0; Wt = Wt0; K = IN_DIM;
            k0 = (i % 12) * 32; n0 = (i / 12) * 32;
        } else {
            int i = b - 8416; W = W1; Wt = Wt1; K = GNN_DIM;
            k0 = (i % 8) * 32; n0 = (i / 8) * 32;
        }
        #pragma unroll
        for (int r = 0; r < 4; ++r)
            tf[ty + r * 8][tx] = W[(size_t)(k0 + ty + r * 8) * GNN_DIM + n0 + tx];
        __syncthreads();
        #pragma unroll
        for (int r = 0; r < 4; ++r)
            Wt[(size_t)(n0 + ty + r * 8) * K + k0 + tx] =
                __float2bfloat16(tf[tx][ty + r * 8]);
    } else if (b < 9000) {
        int nb = (b - 8480) * 16;
        for (int r = 0; r < 16; ++r) {
            int n = nb + r;
            for (int k = tid; k < IN_DIM; k += 256) {
                float v = (n < N_PATCH) ? x[(size_t)n * IN_DIM + k] : ro[k];
                Xb[(size_t)n * IN_DIM + k] = __float2bfloat16(v);
            }
        }
    } else {
        if (tid < N_TILES) {
            int r = ro_ids[tid] - N_PATCH;
            if (r >= 0 && r < N_TILES) outrow[r] = tid;
        }
    }
}

// ---------------------------------------------------------------------------
// Phase A (MFMA): h = Xb @ Wt^T + nemb[node_type]; fused s_src/s_dst/expL.
// Unchanged from R1.
// ---------------------------------------------------------------------------
__global__ __launch_bounds__(256) void phaseA_mfma(
    const __hip_bfloat16* __restrict__ Xb,  // [N_TOT, K] bf16
    const __hip_bfloat16* __restrict__ Wt,  // [256, K] bf16
    int K, int KP,                          // KP = K+8 (LDS row stride)
    const float* __restrict__ nemb,
    const int* __restrict__ node_type,
    const float* __restrict__ asrc, const float* __restrict__ adst,
    const float* __restrict__ ebias,
    float* __restrict__ hP, __hip_bfloat16* __restrict__ hPb,
    float* __restrict__ expL, float* __restrict__ sdst)
{
    __shared__ char smem[16 * 260 * 4];     // 16.6 KB, union of xs / cs
    unsigned short* xs = (unsigned short*)smem;  // [16][KP] bf16 bits
    float* cs = (float*)smem;                    // [16][260] f32

    int tid = threadIdx.x;
    int n0 = blockIdx.x * 16;

    {
        int lr = tid >> 4, lc = tid & 15;
        for (int c = lc * 8; c < K; c += 128)
            *(uint4*)&xs[lr * KP + c] = *(const uint4*)&Xb[(size_t)(n0 + lr) * K + c];
    }
    __syncthreads();

    int wave = tid >> 6, lane = tid & 63;
    int lr16 = lane & 15, quad = lane >> 4;

    f32x4 acc[4];
    #pragma unroll
    for (int ct = 0; ct < 4; ++ct)
        acc[ct] = (f32x4){0.f, 0.f, 0.f, 0.f};

    for (int kc = 0; kc < K; kc += 32) {
        bf16x8 a = *(const bf16x8*)&xs[lr16 * KP + kc + quad * 8];
        #pragma unroll
        for (int ct = 0; ct < 4; ++ct) {
            int col = wave * 64 + ct * 16 + lr16;
            bf16x8 b = *(const bf16x8*)&Wt[(size_t)col * K + kc + quad * 8];
            acc[ct] = __builtin_amdgcn_mfma_f32_16x16x32_bf16(a, b, acc[ct], 0, 0, 0);
        }
    }
    __syncthreads();   // xs dead; reuse as cs

    #pragma unroll
    for (int ct = 0; ct < 4; ++ct)
        #pragma unroll
        for (int g = 0; g < 4; ++g)
            cs[(quad * 4 + g) * 260 + wave * 64 + ct * 16 + lr16] = acc[ct][g];
    __syncthreads();

    int j = tid, h = j >> 6, l2 = j & 63;
    float as = asrc[h * DH + l2];
    float ad = adst[h * DH + l2];
    float eb0 = ebias[0 * HEADS + h], eb1 = ebias[1 * HEADS + h], eb2 = ebias[2 * HEADS + h];
    for (int r = 0; r < 16; ++r) {
        int n = n0 + r;
        float hv = cs[r * 260 + j] + nemb[node_type[n] * GNN_DIM + j];
        hP[(size_t)n * GNN_DIM + j] = hv;
        hPb[(size_t)n * GNN_DIM + j] = __float2bfloat16(hv);
        float ss = waveReduce(hv * as);
        float sd = waveReduce(hv * ad);
        if (l2 == 0) {
            sdst[n * HEADS + h] = sd;
            float l0 = ss + eb0; l0 = l0 > 0.f ? l0 : 0.2f * l0;
            float l1 = ss + eb1; l1 = l1 > 0.f ? l1 : 0.2f * l1;
            float lc2 = ss + eb2; lc2 = lc2 > 0.f ? lc2 : 0.2f * lc2;
            expL[n * 12 + 0 * HEADS + h] = __expf(l0);
            expL[n * 12 + 1 * HEADS + h] = __expf(l1);
            expL[n * 12 + 2 * HEADS + h] = __expf(lc2);
        }
    }
}

// ---------------------------------------------------------------------------
// Phase C FUSED: one block per edge (512 threads), as R1 — but the edge
// message m is now emitted in F32 (float2 per thread) instead of packed
// bf16, removing phaseE's per-element unpack. mb is 1 MB, L2-resident.
// ---------------------------------------------------------------------------
__global__ __launch_bounds__(512) void phaseC_fused(
    const unsigned char* __restrict__ HTb,   // [E, N_TOT/8] bits
    const int* __restrict__ edge_type,
    const float* __restrict__ expL,          // [N,3,4]
    const __hip_bfloat16* __restrict__ hPb,  // [N,256] bf16
    const float* __restrict__ aedg,          // [4,64]
    float* __restrict__ mb, float* __restrict__ sedg)
{
    int e = blockIdx.x, j = threadIdx.x;
    int lane = j & 63, wv = j >> 6;
    __shared__ __align__(16) int   noff[CCAP];
    __shared__ __align__(16) float wh[4][CCAP];
    __shared__ float Zs[4];
    __shared__ float comb[3][128][2];
    __shared__ int   wtot[8];
    __shared__ int   tailc[4];

    const unsigned* Hu = (const unsigned*)(HTb + (size_t)e * NTB);
    int te = edge_type[e];

    unsigned u = (j < 256) ? Hu[j] : 0u;
    int cnt = __popc(u);
    int s = cnt;
    #pragma unroll
    for (int o = 1; o < 64; o <<= 1) {
        int v = __shfl_up(s, o, 64);
        if (lane >= o) s += v;
    }
    if (lane == 63) wtot[wv] = s;
    if (j < 4) tailc[j] = __popc(Hu[256 + j]);
    __syncthreads();

    int base = 0, mainTot = 0;
    #pragma unroll
    for (int w = 0; w < 8; ++w) {
        int t = wtot[w];
        if (w < wv) base += t;
        mainTot += t;
    }
    int cfull = mainTot + tailc[0] + tailc[1] + tailc[2] + tailc[3];
    int c = min(cfull, CCAP - 16);
    {
        int off = base + s - cnt;
        int nb = j << 5;
        while (u) {
            int i = __ffs(u) - 1; u &= u - 1;
            if (off < CCAP) noff[off] = (nb + i) << 9;
            ++off;
        }
        if (j < 4) {
            int tb = mainTot;
            for (int k = 0; k < j; ++k) tb += tailc[k];
            unsigned ut = Hu[256 + j];
            int nb2 = (256 + j) << 5;
            while (ut) {
                int i = __ffs(ut) - 1; ut &= ut - 1;
                if (tb < CCAP) noff[tb] = (nb2 + i) << 9;
                ++tb;
            }
        }
    }
    __syncthreads();

    int cP = (c + 15) & ~15;
    for (int i = j; i < c; i += 512) {
        int n = noff[i] >> 9;
        float4 w = *(const float4*)&expL[n * 12 + te * 4];
        wh[0][i] = w.x; wh[1][i] = w.y; wh[2][i] = w.z; wh[3][i] = w.w;
    }
    if (j < 16) {
        int i = c + j;
        if (i < cP) { noff[i] = 0; wh[0][i] = wh[1][i] = wh[2][i] = wh[3][i] = 0.f; }
    }
    __syncthreads();

    if (j < 256) {
        float p = 0.f;
        for (int i = lane; i < c; i += 64) p += wh[wv][i];
        p = waveReduce(p);
        if (lane == 0) Zs[wv] = p;
    }
    __syncthreads();

    int q = j >> 7, p = j & 127, h2 = p >> 5;
    const char* hb = (const char*)hPb;
    int coff = p << 2;
    float al0 = 0.f, ah0 = 0.f, al1 = 0.f, ah1 = 0.f;
    for (int i = q * 4; i < cP; i += 16) {
        int4   n4 = *(const int4*)&noff[i];
        float4 w4 = *(const float4*)&wh[h2][i];
        unsigned u0 = *(const unsigned*)(hb + n4.x + coff);
        unsigned u1 = *(const unsigned*)(hb + n4.y + coff);
        unsigned u2 = *(const unsigned*)(hb + n4.z + coff);
        unsigned u3 = *(const unsigned*)(hb + n4.w + coff);
        al0 += w4.x * bflo(u0); ah0 += w4.x * bfhi(u0);
        al1 += w4.y * bflo(u1); ah1 += w4.y * bfhi(u1);
        al0 += w4.z * bflo(u2); ah0 += w4.z * bfhi(u2);
        al1 += w4.w * bflo(u3); ah1 += w4.w * bfhi(u3);
    }
    float s0 = al0 + al1, s1 = ah0 + ah1;
    if (q > 0) { comb[q - 1][p][0] = s0; comb[q - 1][p][1] = s1; }
    __syncthreads();
    if (q == 0) {
        s0 += comb[0][p][0] + comb[1][p][0] + comb[2][p][0];
        s1 += comb[0][p][1] + comb[1][p][1] + comb[2][p][1];
        float Zi = 1.f / Zs[h2];
        float mv0 = s0 * Zi, mv1 = s1 * Zi;
        float2 mv; mv.x = mv0; mv.y = mv1;
        *(float2*)&mb[(size_t)e * GNN_DIM + 2 * p] = mv;   // f32 message
        int d0 = (p & 31) << 1;
        float se = mv0 * aedg[h2 * DH + d0] + mv1 * aedg[h2 * DH + d0 + 1];
        #pragma unroll
        for (int o = 16; o > 0; o >>= 1) se += __shfl_down(se, o, 32);
        if ((p & 31) == 0) sedg[e * HEADS + h2] = se;
    }
}

// ---------------------------------------------------------------------------
// Phase E (layer 0): R1 block-per-node structure (proven 59% occupancy),
// gather loads are now float2 from f32 mb — unpack ops eliminated.
// ---------------------------------------------------------------------------
__global__ __launch_bounds__(256) void phaseE(
    const unsigned char* __restrict__ HNb,   // [N, E/8] bits
    const float* __restrict__ sdstArr,       // [N,4]
    const float* __restrict__ sedg,          // [E,4]
    const float* __restrict__ mb,            // [E,256] f32
    const float* __restrict__ hP,            // [N,256] residual
    __hip_bfloat16* __restrict__ hOutb)
{
    int n = blockIdx.x, j = threadIdx.x;
    int lane = j & 63, wv = j >> 6;
    __shared__ int cnt;
    __shared__ __align__(16) int   eidx[ECAP];   // edge byte-offsets (e<<10)
    __shared__ __align__(16) float wh[4][ECAP];
    __shared__ float Zs[4];
    __shared__ float comb[128][2];
    __shared__ float sdv[4];
    if (j < 4) sdv[j] = sdstArr[n * HEADS + j];
    if (j == 0) cnt = 0;
    __syncthreads();
    if (j < 32) {
        unsigned b = ((const unsigned*)(HNb + (size_t)n * NEB))[j];
        int eb = j << 5;
        while (b) {
            int i = __ffs(b) - 1; b &= b - 1;
            int p = atomicAdd(&cnt, 1);
            eidx[p] = (eb + i) << 10;            // f32 row = 1024 B
        }
    }
    __syncthreads();
    int c = cnt;
    int cP = (c + 7) & ~7;
    for (int i = j; i < c; i += 256) {
        int e = eidx[i] >> 10;
        float4 sg = *(const float4*)&sedg[e * 4];
        float l0 = sdv[0] + sg.x; l0 = l0 > 0.f ? l0 : 0.2f * l0;
        float l1 = sdv[1] + sg.y; l1 = l1 > 0.f ? l1 : 0.2f * l1;
        float l2 = sdv[2] + sg.z; l2 = l2 > 0.f ? l2 : 0.2f * l2;
        float l3 = sdv[3] + sg.w; l3 = l3 > 0.f ? l3 : 0.2f * l3;
        wh[0][i] = __expf(l0); wh[1][i] = __expf(l1);
        wh[2][i] = __expf(l2); wh[3][i] = __expf(l3);
    }
    if (j < 8) {
        int i = c + j;
        if (i < cP) { eidx[i] = 0; wh[0][i] = wh[1][i] = wh[2][i] = wh[3][i] = 0.f; }
    }
    __syncthreads();
    {
        float p = 0.f;
        for (int i = lane; i < c; i += 64) p += wh[wv][i];
        p = waveReduce(p);
        if (lane == 0) Zs[wv] = p;
    }
    __syncthreads();

    int par = j >> 7, p = j & 127, h2 = p >> 5;
    const char* mbb = (const char*)mb;
    int coff = p << 3;                       // float2 per 2 cols
    float a0 = 0.f, b0 = 0.f, a1 = 0.f, b1 = 0.f;
    for (int i = par * 4; i < cP; i += 8) {
        int4   e4 = *(const int4*)&eidx[i];
        float4 w4 = *(const float4*)&wh[h2][i];
        float2 v0 = *(const float2*)(mbb + e4.x + coff);
        float2 v1 = *(const float2*)(mbb + e4.y + coff);
        float2 v2 = *(const float2*)(mbb + e4.z + coff);
        float2 v3 = *(const float2*)(mbb + e4.w + coff);
        a0 += w4.x * v0.x; b0 += w4.x * v0.y;
        a1 += w4.y * v1.x; b1 += w4.y * v1.y;
        a0 += w4.z * v2.x; b0 += w4.z * v2.y;
        a1 += w4.w * v3.x; b1 += w4.w * v3.y;
    }
    if (par == 1) { comb[p][0] = a0 + a1; comb[p][1] = b0 + b1; }
    __syncthreads();
    if (par == 0) {
        float o0 = a0 + a1 + comb[p][0];
        float o1 = b0 + b1 + comb[p][1];
        float Zi = 1.f / Zs[h2];
        o0 *= Zi; o1 *= Zi;
        o0 = o0 > 0.f ? o0 : expm1f(o0);   // ELU (alpha=1)
        o1 = o1 > 0.f ? o1 : expm1f(o1);
        float2 hr = *(const float2*)&hP[(size_t)n * GNN_DIM + 2 * p];
        ((unsigned*)hOutb)[n * 128 + p] = packbf2(o0 + hr.x, o1 + hr.y);
    }
}

// ---------------------------------------------------------------------------
// Phase E last (layer 1): same gather body (f32 mb) + fused final layernorm.
// ---------------------------------------------------------------------------
__global__ __launch_bounds__(256) void phaseE_last(
    const unsigned char* __restrict__ HNb,
    const float* __restrict__ sdstArr,
    const float* __restrict__ sedg,
    const float* __restrict__ mb,            // [E,256] f32
    const float* __restrict__ hP,
    const float* __restrict__ ng, const float* __restrict__ nbeta,
    const float* __restrict__ bg, const float* __restrict__ bbeta,
    const int* __restrict__ outrow,
    float* __restrict__ out)
{
    int n = blockIdx.x, j = threadIdx.x;
    int lane = j & 63, wv = j >> 6;
    __shared__ int cnt;
    __shared__ __align__(16) int   eidx[ECAP];
    __shared__ __align__(16) float wh[4][ECAP];
    __shared__ float Zs[4];
    __shared__ float comb[128][2];
    __shared__ float sdv[4];
    __shared__ float red[4];
    if (j < 4) sdv[j] = sdstArr[n * HEADS + j];
    if (j == 0) cnt = 0;
    __syncthreads();
    if (j < 32) {
        unsigned b = ((const unsigned*)(HNb + (size_t)n * NEB))[j];
        int eb = j << 5;
        while (b) {
            int i = __ffs(b) - 1; b &= b - 1;
            int p = atomicAdd(&cnt, 1);
            eidx[p] = (eb + i) << 10;
        }
    }
    __syncthreads();
    int c = cnt;
    int cP = (c + 7) & ~7;
    for (int i = j; i < c; i += 256) {
        int e = eidx[i] >> 10;
        float4 sg = *(const float4*)&sedg[e * 4];
        float l0 = sdv[0] + sg.x; l0 = l0 > 0.f ? l0 : 0.2f * l0;
        float l1 = sdv[1] + sg.y; l1 = l1 > 0.f ? l1 : 0.2f * l1;
        float l2 = sdv[2] + sg.z; l2 = l2 > 0.f ? l2 : 0.2f * l2;
        float l3 = sdv[3] + sg.w; l3 = l3 > 0.f ? l3 : 0.2f * l3;
        wh[0][i] = __expf(l0); wh[1][i] = __expf(l1);
        wh[2][i] = __expf(l2); wh[3][i] = __expf(l3);
    }
    if (j < 8) {
        int i = c + j;
        if (i < cP) { eidx[i] = 0; wh[0][i] = wh[1][i] = wh[2][i] = wh[3][i] = 0.f; }
    }
    __syncthreads();
    {
        float p = 0.f;
        for (int i = lane; i < c; i += 64) p += wh[wv][i];
        p = waveReduce(p);
        if (lane == 0) Zs[wv] = p;
    }
    __syncthreads();

    int par = j >> 7, p = j & 127, h2 = p >> 5;
    const char* mbb = (const char*)mb;
    int coff = p << 3;
    float a0 = 0.f, b0 = 0.f, a1 = 0.f, b1 = 0.f;
    for (int i = par * 4; i < cP; i += 8) {
        int4   e4 = *(const int4*)&eidx[i];
        float4 w4 = *(const float4*)&wh[h2][i];
        float2 v0 = *(const float2*)(mbb + e4.x + coff);
        float2 v1 = *(const float2*)(mbb + e4.y + coff);
        float2 v2 = *(const float2*)(mbb + e4.z + coff);
        float2 v3 = *(const float2*)(mbb + e4.w + coff);
        a0 += w4.x * v0.x; b0 += w4.x * v0.y;
        a1 += w4.y * v1.x; b1 += w4.y * v1.y;
        a0 += w4.z * v2.x; b0 += w4.z * v2.y;
        a1 += w4.w * v3.x; b1 += w4.w * v3.y;
    }
    if (par == 1) { comb[p][0] = a0 + a1; comb[p][1] = b0 + b1; }
    __syncthreads();

    float r0 = 0.f, r1 = 0.f;
    if (par == 0) {
        float o0 = a0 + a1 + comb[p][0];
        float o1 = b0 + b1 + comb[p][1];
        float Zi = 1.f / Zs[h2];
        o0 *= Zi; o1 *= Zi;
        o0 = o0 > 0.f ? o0 : expm1f(o0);
        o1 = o1 > 0.f ? o1 : expm1f(o1);
        float2 hr = *(const float2*)&hP[(size_t)n * GNN_DIM + 2 * p];
        r0 = o0 + hr.x; r1 = o1 + hr.y;
    }

    // fused layernorm over this node's 256 columns (par==1 contributes 0)
    float sm = waveReduce(r0 + r1);
    if (lane == 0) red[wv] = sm;
    __syncthreads();
    float mean = (red[0] + red[1] + red[2] + red[3]) * (1.f / GNN_DIM);
    __syncthreads();
    float d0 = r0 - mean, d1 = r1 - mean;
    float sv = (par == 0) ? (d0 * d0 + d1 * d1) : 0.f;
    sv = waveReduce(sv);
    if (lane == 0) red[wv] = sv;
    __syncthreads();
    float var = (red[0] + red[1] + red[2] + red[3]) * (1.f / GNN_DIM);
    if (par == 0) {
        const float* g; const float* bta; size_t outOff;
        if (n < N_PATCH) { g = ng; bta = nbeta; outOff = (size_t)n * GNN_DIM; }
        else {
            int qq = outrow[n - N_PATCH];
            g = bg; bta = bbeta;
            outOff = (size_t)(N_PATCH + qq) * GNN_DIM;
        }
        float is = rsqrtf(var + 1e-5f);
        float2 gv = *(const float2*)&g[2 * p];
        float2 bv = *(const float2*)&bta[2 * p];
        float2 ov; ov.x = d0 * is * gv.x + bv.x; ov.y = d1 * is * gv.y + bv.y;
        *(float2*)&out[outOff + 2 * p] = ov;
    }
}

// ---------------------------------------------------------------------------
extern "C" void kernel_launch(void* const* d_in, const int* in_sizes, int n_in,
                              void* d_out, int out_size, void* d_ws, size_t ws_size,
                              hipStream_t stream) {
    const float* x_nodes   = (const float*)d_in[0];
    const float* readout   = (const float*)d_in[1];
    const int*   node_type = (const int*)d_in[2];
    const int*   edge_type = (const int*)d_in[3];
    const float* Hmat      = (const float*)d_in[4];
    const int*   ro_ids    = (const int*)d_in[5];
    const float* W0        = (const float*)d_in[6];
    const float* W1        = (const float*)d_in[7];
    const float* node_emb  = (const float*)d_in[8];
    const float* a_src     = (const float*)d_in[9];
    const float* a_dst     = (const float*)d_in[10];
    const float* a_edge    = (const float*)d_in[11];
    const float* edge_bias = (const float*)d_in[12];
    const float* node_g    = (const float*)d_in[13];
    const float* node_b    = (const float*)d_in[14];
    const float* bag_g     = (const float*)d_in[15];
    const float* bag_b     = (const float*)d_in[16];

    // Workspace layout (~23.2 MB; mb now f32 = 1 MB)
    char* ws = (char*)d_ws;
    size_t off = 0;
    unsigned char* HTb = (unsigned char*)(ws + off); off += (size_t)N_EDGES * NTB;
    unsigned char* HNb = (unsigned char*)(ws + off); off += (size_t)N_TOT * NEB;
    off = (off + 255) & ~(size_t)255;
    float* hP   = (float*)(ws + off); off += (size_t)N_TOT * GNN_DIM * 4;
    __hip_bfloat16* hPb = (__hip_bfloat16*)(ws + off); off += (size_t)N_TOT * GNN_DIM * 2;
    float* mb   = (float*)(ws + off); off += (size_t)N_EDGES * GNN_DIM * 4;
    __hip_bfloat16* Xb0 = (__hip_bfloat16*)(ws + off); off += (size_t)N_TOT * IN_DIM * 2;
    __hip_bfloat16* Wt0 = (__hip_bfloat16*)(ws + off); off += (size_t)GNN_DIM * IN_DIM * 2;
    __hip_bfloat16* Wt1 = (__hip_bfloat16*)(ws + off); off += (size_t)GNN_DIM * GNN_DIM * 2;
    float* expL = (float*)(ws + off); off += (size_t)N_TOT * 12 * 4;
    float* sdst = (float*)(ws + off); off += (size_t)N_TOT * HEADS * 4;
    float* sedg = (float*)(ws + off); off += (size_t)N_EDGES * HEADS * 4;
    int* outrow = (int*)(ws + off); off += N_TILES * 4;
    __hip_bfloat16* hXb = Xb0;               // alias (Xb0 dead after layer-0 phaseA)

    // ----- fused prep -----
    prep1<<<9001, 256, 0, stream>>>(Hmat, HTb, HNb, W0, Wt0, W1, Wt1,
                                    x_nodes, readout, Xb0, ro_ids, outrow);

    // ----- layer 0 -----
    phaseA_mfma<<<N_TOT / 16, 256, 0, stream>>>(Xb0, Wt0, IN_DIM, IN_DIM + 8,
                                      node_emb, node_type,
                                      a_src, a_dst, edge_bias,
                                      hP, hPb, expL, sdst);
    phaseC_fused<<<N_EDGES, 512, 0, stream>>>(HTb, edge_type, expL, hPb,
                                              a_edge, mb, sedg);
    phaseE<<<N_TOT, 256, 0, stream>>>(HNb, sdst, sedg, mb, hP, hXb);

    // ----- layer 1 -----
    phaseA_mfma<<<N_TOT / 16, 256, 0, stream>>>(hXb, Wt1, GNN_DIM, GNN_DIM + 8,
                                      node_emb + 4 * GNN_DIM, node_type,
                                      a_src + HEADS * DH, a_dst + HEADS * DH,
                                      edge_bias + 12,
                                      hP, hPb, expL, sdst);
    phaseC_fused<<<N_EDGES, 512, 0, stream>>>(HTb, edge_type, expL, hPb,
                                              a_edge + HEADS * DH, mb, sedg);
    phaseE_last<<<N_TOT, 256, 0, stream>>>(HNb, sdst, sedg, mb, hP,
                                           node_g, node_b, bag_g, bag_b, outrow,
                                           (float*)d_out);
}

// Round 7
// 299.011 us; speedup vs baseline: 2.1942x; 1.1008x over previous
//
#include <hip/hip_runtime.h>
#include <hip/hip_bf16.h>
#include <math.h>

// Problem constants
#define IN_DIM   384
#define GNN_DIM  256
#define HEADS    4
#define DH       64
#define N_PATCH  8192
#define N_TILES  128
#define N_EDGES  1024
#define N_TOT    (N_PATCH + N_TILES)   // 8320
#define NTB      (N_TOT / 8)           // 1040 bytes per HTb row
#define NEB      (N_EDGES / 8)         // 128 bytes per HNb row
#define CCAP     800                   // phaseC member capacity
#define ECAP     1032                  // phaseE edge capacity (max 1024 + pad)

typedef short  bf16x8 __attribute__((ext_vector_type(8)));
typedef float  f32x4  __attribute__((ext_vector_type(4)));

// ---------------------------------------------------------------------------
__device__ __forceinline__ float waveReduce(float v) {
    #pragma unroll
    for (int o = 32; o > 0; o >>= 1) v += __shfl_down(v, o, 64);
    return v; // valid in lane 0 of each 64-wide wave
}
__device__ __forceinline__ float bflo(unsigned u) { return __uint_as_float(u << 16); }
__device__ __forceinline__ float bfhi(unsigned u) { return __uint_as_float(u & 0xffff0000u); }
__device__ __forceinline__ unsigned packbf2(float a, float b) {
    __hip_bfloat16 b0 = __float2bfloat16(a), b1 = __float2bfloat16(b);
    unsigned short u0, u1;
    __builtin_memcpy(&u0, &b0, 2);
    __builtin_memcpy(&u1, &b1, 2);
    return (unsigned)u0 | ((unsigned)u1 << 16);
}
// ELU negative branch: __expf-1 instead of expm1f (libm poly) — saves ~20 VALU,
// abs error ~1e-7, invisible at bf16-quantized absmax 0.03125.
__device__ __forceinline__ float eluNeg(float x) { return __expf(x) - 1.f; }

// ---------------------------------------------------------------------------
// Fused prep kernel (grid-partitioned): unchanged from R1 (298.5us baseline).
// ---------------------------------------------------------------------------
__global__ __launch_bounds__(256) void prep1(
    const float* __restrict__ H,
    unsigned char* __restrict__ HTb, unsigned char* __restrict__ HNb,
    const float* __restrict__ W0, __hip_bfloat16* __restrict__ Wt0,
    const float* __restrict__ W1, __hip_bfloat16* __restrict__ Wt1,
    const float* __restrict__ x, const float* __restrict__ ro,
    __hip_bfloat16* __restrict__ Xb,
    const int* __restrict__ ro_ids, int* __restrict__ outrow)
{
    __shared__ unsigned char tb[32][33];
    __shared__ float tf[32][33];
    int b = blockIdx.x, tid = threadIdx.x;
    int tx = tid & 31, ty = tid >> 5;          // ty in 0..7

    if (b < 8320) {
        int n0 = (b % 260) * 32;
        int e0 = (b / 260) * 32;
        #pragma unroll
        for (int r = 0; r < 4; ++r) {
            int row = ty + r * 8;
            tb[row][tx] = (H[(size_t)(n0 + row) * N_EDGES + e0 + tx] > 0.f) ? 1 : 0;
        }
        __syncthreads();
        if (tid < 128) {            // HTb: 32 edges x 4 node-bytes
            int er = tid >> 2, g = tid & 3;
            unsigned v = 0;
            #pragma unroll
            for (int i = 0; i < 8; ++i) v |= (unsigned)tb[g * 8 + i][er] << i;
            HTb[(size_t)(e0 + er) * NTB + (n0 >> 3) + g] = (unsigned char)v;
        } else {                    // HNb: 32 nodes x 4 edge-bytes
            int id = tid - 128;
            int nr = id >> 2, g = id & 3;
            unsigned v = 0;
            #pragma unroll
            for (int i = 0; i < 8; ++i) v |= (unsigned)tb[nr][g * 8 + i] << i;
            HNb[(size_t)(n0 + nr) * NEB + (e0 >> 3) + g] = (unsigned char)v;
        }
    } else if (b < 8480) {
        const float* W; __hip_bfloat16* Wt; int K, k0, n0;
        if (b < 8416) {
            int i = b - 8320; W = W0; Wt = Wt0; K = IN_DIM;
            k0 = (i % 12) * 32; n0 = (i / 12) * 32;
        } else {
            int i = b - 8416; W = W1; Wt = Wt1; K = GNN_DIM;
            k0 = (i % 8) * 32; n0 = (i / 8) * 32;
        }
        #pragma unroll
        for (int r = 0; r < 4; ++r)
            tf[ty + r * 8][tx] = W[(size_t)(k0 + ty + r * 8) * GNN_DIM + n0 + tx];
        __syncthreads();
        #pragma unroll
        for (int r = 0; r < 4; ++r)
            Wt[(size_t)(n0 + ty + r * 8) * K + k0 + tx] =
                __float2bfloat16(tf[tx][ty + r * 8]);
    } else if (b < 9000) {
        int nb = (b - 8480) * 16;
        for (int r = 0; r < 16; ++r) {
            int n = nb + r;
            for (int k = tid; k < IN_DIM; k += 256) {
                float v = (n < N_PATCH) ? x[(size_t)n * IN_DIM + k] : ro[k];
                Xb[(size_t)n * IN_DIM + k] = __float2bfloat16(v);
            }
        }
    } else {
        if (tid < N_TILES) {
            int r = ro_ids[tid] - N_PATCH;
            if (r >= 0 && r < N_TILES) outrow[r] = tid;
        }
    }
}

// ---------------------------------------------------------------------------
// Phase A (MFMA): h = Xb @ Wt^T + nemb[node_type]; fused s_src/s_dst/expL.
// Unchanged from R1.
// ---------------------------------------------------------------------------
__global__ __launch_bounds__(256) void phaseA_mfma(
    const __hip_bfloat16* __restrict__ Xb,  // [N_TOT, K] bf16
    const __hip_bfloat16* __restrict__ Wt,  // [256, K] bf16
    int K, int KP,                          // KP = K+8 (LDS row stride)
    const float* __restrict__ nemb,
    const int* __restrict__ node_type,
    const float* __restrict__ asrc, const float* __restrict__ adst,
    const float* __restrict__ ebias,
    float* __restrict__ hP, __hip_bfloat16* __restrict__ hPb,
    float* __restrict__ expL, float* __restrict__ sdst)
{
    __shared__ char smem[16 * 260 * 4];     // 16.6 KB, union of xs / cs
    unsigned short* xs = (unsigned short*)smem;  // [16][KP] bf16 bits
    float* cs = (float*)smem;                    // [16][260] f32

    int tid = threadIdx.x;
    int n0 = blockIdx.x * 16;

    {
        int lr = tid >> 4, lc = tid & 15;
        for (int c = lc * 8; c < K; c += 128)
            *(uint4*)&xs[lr * KP + c] = *(const uint4*)&Xb[(size_t)(n0 + lr) * K + c];
    }
    __syncthreads();

    int wave = tid >> 6, lane = tid & 63;
    int lr16 = lane & 15, quad = lane >> 4;

    f32x4 acc[4];
    #pragma unroll
    for (int ct = 0; ct < 4; ++ct)
        acc[ct] = (f32x4){0.f, 0.f, 0.f, 0.f};

    for (int kc = 0; kc < K; kc += 32) {
        bf16x8 a = *(const bf16x8*)&xs[lr16 * KP + kc + quad * 8];
        #pragma unroll
        for (int ct = 0; ct < 4; ++ct) {
            int col = wave * 64 + ct * 16 + lr16;
            bf16x8 b = *(const bf16x8*)&Wt[(size_t)col * K + kc + quad * 8];
            acc[ct] = __builtin_amdgcn_mfma_f32_16x16x32_bf16(a, b, acc[ct], 0, 0, 0);
        }
    }
    __syncthreads();   // xs dead; reuse as cs

    #pragma unroll
    for (int ct = 0; ct < 4; ++ct)
        #pragma unroll
        for (int g = 0; g < 4; ++g)
            cs[(quad * 4 + g) * 260 + wave * 64 + ct * 16 + lr16] = acc[ct][g];
    __syncthreads();

    int j = tid, h = j >> 6, l2 = j & 63;
    float as = asrc[h * DH + l2];
    float ad = adst[h * DH + l2];
    float eb0 = ebias[0 * HEADS + h], eb1 = ebias[1 * HEADS + h], eb2 = ebias[2 * HEADS + h];
    for (int r = 0; r < 16; ++r) {
        int n = n0 + r;
        float hv = cs[r * 260 + j] + nemb[node_type[n] * GNN_DIM + j];
        hP[(size_t)n * GNN_DIM + j] = hv;
        hPb[(size_t)n * GNN_DIM + j] = __float2bfloat16(hv);
        float ss = waveReduce(hv * as);
        float sd = waveReduce(hv * ad);
        if (l2 == 0) {
            sdst[n * HEADS + h] = sd;
            float l0 = ss + eb0; l0 = l0 > 0.f ? l0 : 0.2f * l0;
            float l1 = ss + eb1; l1 = l1 > 0.f ? l1 : 0.2f * l1;
            float lc2 = ss + eb2; lc2 = lc2 > 0.f ? lc2 : 0.2f * lc2;
            expL[n * 12 + 0 * HEADS + h] = __expf(l0);
            expL[n * 12 + 1 * HEADS + h] = __expf(l1);
            expL[n * 12 + 2 * HEADS + h] = __expf(lc2);
        }
    }
}

// ---------------------------------------------------------------------------
// Phase C FUSED: unchanged from R1 (one block per edge, 512 threads,
// bf16 mb output — R6 A/B proved bf16 strictly better than f32).
// ---------------------------------------------------------------------------
__global__ __launch_bounds__(512) void phaseC_fused(
    const unsigned char* __restrict__ HTb,   // [E, N_TOT/8] bits
    const int* __restrict__ edge_type,
    const float* __restrict__ expL,          // [N,3,4]
    const __hip_bfloat16* __restrict__ hPb,  // [N,256] bf16
    const float* __restrict__ aedg,          // [4,64]
    __hip_bfloat16* __restrict__ mb, float* __restrict__ sedg)
{
    int e = blockIdx.x, j = threadIdx.x;
    int lane = j & 63, wv = j >> 6;
    __shared__ __align__(16) int   noff[CCAP];
    __shared__ __align__(16) float wh[4][CCAP];
    __shared__ float Zs[4];
    __shared__ float comb[3][128][2];
    __shared__ int   wtot[8];
    __shared__ int   tailc[4];

    const unsigned* Hu = (const unsigned*)(HTb + (size_t)e * NTB);
    int te = edge_type[e];

    unsigned u = (j < 256) ? Hu[j] : 0u;
    int cnt = __popc(u);
    int s = cnt;
    #pragma unroll
    for (int o = 1; o < 64; o <<= 1) {
        int v = __shfl_up(s, o, 64);
        if (lane >= o) s += v;
    }
    if (lane == 63) wtot[wv] = s;
    if (j < 4) tailc[j] = __popc(Hu[256 + j]);
    __syncthreads();

    int base = 0, mainTot = 0;
    #pragma unroll
    for (int w = 0; w < 8; ++w) {
        int t = wtot[w];
        if (w < wv) base += t;
        mainTot += t;
    }
    int cfull = mainTot + tailc[0] + tailc[1] + tailc[2] + tailc[3];
    int c = min(cfull, CCAP - 16);
    {
        int off = base + s - cnt;
        int nb = j << 5;
        while (u) {
            int i = __ffs(u) - 1; u &= u - 1;
            if (off < CCAP) noff[off] = (nb + i) << 9;
            ++off;
        }
        if (j < 4) {
            int tb = mainTot;
            for (int k = 0; k < j; ++k) tb += tailc[k];
            unsigned ut = Hu[256 + j];
            int nb2 = (256 + j) << 5;
            while (ut) {
                int i = __ffs(ut) - 1; ut &= ut - 1;
                if (tb < CCAP) noff[tb] = (nb2 + i) << 9;
                ++tb;
            }
        }
    }
    __syncthreads();

    int cP = (c + 15) & ~15;
    for (int i = j; i < c; i += 512) {
        int n = noff[i] >> 9;
        float4 w = *(const float4*)&expL[n * 12 + te * 4];
        wh[0][i] = w.x; wh[1][i] = w.y; wh[2][i] = w.z; wh[3][i] = w.w;
    }
    if (j < 16) {
        int i = c + j;
        if (i < cP) { noff[i] = 0; wh[0][i] = wh[1][i] = wh[2][i] = wh[3][i] = 0.f; }
    }
    __syncthreads();

    if (j < 256) {
        float p = 0.f;
        for (int i = lane; i < c; i += 64) p += wh[wv][i];
        p = waveReduce(p);
        if (lane == 0) Zs[wv] = p;
    }
    __syncthreads();

    int q = j >> 7, p = j & 127, h2 = p >> 5;
    const char* hb = (const char*)hPb;
    int coff = p << 2;
    float al0 = 0.f, ah0 = 0.f, al1 = 0.f, ah1 = 0.f;
    for (int i = q * 4; i < cP; i += 16) {
        int4   n4 = *(const int4*)&noff[i];
        float4 w4 = *(const float4*)&wh[h2][i];
        unsigned u0 = *(const unsigned*)(hb + n4.x + coff);
        unsigned u1 = *(const unsigned*)(hb + n4.y + coff);
        unsigned u2 = *(const unsigned*)(hb + n4.z + coff);
        unsigned u3 = *(const unsigned*)(hb + n4.w + coff);
        al0 += w4.x * bflo(u0); ah0 += w4.x * bfhi(u0);
        al1 += w4.y * bflo(u1); ah1 += w4.y * bfhi(u1);
        al0 += w4.z * bflo(u2); ah0 += w4.z * bfhi(u2);
        al1 += w4.w * bflo(u3); ah1 += w4.w * bfhi(u3);
    }
    float s0 = al0 + al1, s1 = ah0 + ah1;
    if (q > 0) { comb[q - 1][p][0] = s0; comb[q - 1][p][1] = s1; }
    __syncthreads();
    if (q == 0) {
        s0 += comb[0][p][0] + comb[1][p][0] + comb[2][p][0];
        s1 += comb[0][p][1] + comb[1][p][1] + comb[2][p][1];
        float Zi = 1.f / Zs[h2];
        float mv0 = s0 * Zi, mv1 = s1 * Zi;
        ((unsigned*)mb)[e * 128 + p] = packbf2(mv0, mv1);
        int d0 = (p & 31) << 1;
        float se = mv0 * aedg[h2 * DH + d0] + mv1 * aedg[h2 * DH + d0 + 1];
        #pragma unroll
        for (int o = 16; o > 0; o >>= 1) se += __shfl_down(se, o, 32);
        if ((p & 31) == 0) sedg[e * HEADS + h2] = se;
    }
}

// ---------------------------------------------------------------------------
// Phase E (layer 0): R1 block-per-node structure (proven best) with two
// critical-path cuts: (a) wave-scan compaction, atomic-free + sorted
// (ascending e -> streaming mb access); (b) __expf-1 ELU.
// ---------------------------------------------------------------------------
__global__ __launch_bounds__(256) void phaseE(
    const unsigned char* __restrict__ HNb,   // [N, E/8] bits
    const float* __restrict__ sdstArr,       // [N,4]
    const float* __restrict__ sedg,          // [E,4]
    const __hip_bfloat16* __restrict__ mb,   // [E,256] bf16
    const float* __restrict__ hP,            // [N,256] residual
    __hip_bfloat16* __restrict__ hOutb)
{
    int n = blockIdx.x, j = threadIdx.x;
    int lane = j & 63, wv = j >> 6;
    __shared__ int cntS;
    __shared__ __align__(16) int   eidx[ECAP];   // sorted edge byte-offsets (e<<9)
    __shared__ __align__(16) float wh[4][ECAP];
    __shared__ float Zs[4];
    __shared__ float comb[128][2];
    __shared__ float sdv[4];
    if (j < 4) sdv[j] = sdstArr[n * HEADS + j];
    // wave 0: popcount + prefix-scan compaction (no LDS atomics, sorted)
    if (j < 64) {
        unsigned b = (j < 32) ? ((const unsigned*)(HNb + (size_t)n * NEB))[j] : 0u;
        int cnt0 = __popc(b);
        int s = cnt0;
        #pragma unroll
        for (int o = 1; o < 64; o <<= 1) {
            int v = __shfl_up(s, o, 64);
            if (j >= o) s += v;
        }
        if (j == 63) cntS = s;
        int off = s - cnt0, eb = j << 5;
        while (b) {
            int i = __ffs(b) - 1; b &= b - 1;
            eidx[off++] = (eb + i) << 9;
        }
    }
    __syncthreads();
    int c = cntS;
    int cP = (c + 7) & ~7;
    for (int i = j; i < c; i += 256) {
        int e = eidx[i] >> 9;
        float4 sg = *(const float4*)&sedg[e * 4];
        float l0 = sdv[0] + sg.x; l0 = l0 > 0.f ? l0 : 0.2f * l0;
        float l1 = sdv[1] + sg.y; l1 = l1 > 0.f ? l1 : 0.2f * l1;
        float l2 = sdv[2] + sg.z; l2 = l2 > 0.f ? l2 : 0.2f * l2;
        float l3 = sdv[3] + sg.w; l3 = l3 > 0.f ? l3 : 0.2f * l3;
        wh[0][i] = __expf(l0); wh[1][i] = __expf(l1);
        wh[2][i] = __expf(l2); wh[3][i] = __expf(l3);
    }
    if (j < 8) {
        int i = c + j;
        if (i < cP) { eidx[i] = 0; wh[0][i] = wh[1][i] = wh[2][i] = wh[3][i] = 0.f; }
    }
    __syncthreads();
    {
        float p = 0.f;
        for (int i = lane; i < c; i += 64) p += wh[wv][i];
        p = waveReduce(p);
        if (lane == 0) Zs[wv] = p;
    }
    __syncthreads();

    int par = j >> 7, p = j & 127, h2 = p >> 5;
    const char* mbb = (const char*)mb;
    int coff = p << 2;
    float a0 = 0.f, b0 = 0.f, a1 = 0.f, b1 = 0.f;
    for (int i = par * 4; i < cP; i += 8) {
        int4   e4 = *(const int4*)&eidx[i];
        float4 w4 = *(const float4*)&wh[h2][i];
        unsigned u0 = *(const unsigned*)(mbb + e4.x + coff);
        unsigned u1 = *(const unsigned*)(mbb + e4.y + coff);
        unsigned u2 = *(const unsigned*)(mbb + e4.z + coff);
        unsigned u3 = *(const unsigned*)(mbb + e4.w + coff);
        a0 += w4.x * bflo(u0); b0 += w4.x * bfhi(u0);
        a1 += w4.y * bflo(u1); b1 += w4.y * bfhi(u1);
        a0 += w4.z * bflo(u2); b0 += w4.z * bfhi(u2);
        a1 += w4.w * bflo(u3); b1 += w4.w * bfhi(u3);
    }
    if (par == 1) { comb[p][0] = a0 + a1; comb[p][1] = b0 + b1; }
    __syncthreads();
    if (par == 0) {
        float o0 = a0 + a1 + comb[p][0];
        float o1 = b0 + b1 + comb[p][1];
        float Zi = 1.f / Zs[h2];
        o0 *= Zi; o1 *= Zi;
        o0 = o0 > 0.f ? o0 : eluNeg(o0);   // ELU (alpha=1)
        o1 = o1 > 0.f ? o1 : eluNeg(o1);
        float2 hr = *(const float2*)&hP[(size_t)n * GNN_DIM + 2 * p];
        ((unsigned*)hOutb)[n * 128 + p] = packbf2(o0 + hr.x, o1 + hr.y);
    }
}

// ---------------------------------------------------------------------------
// Phase E last (layer 1): same cuts + fused final layernorm -> d_out.
// ---------------------------------------------------------------------------
__global__ __launch_bounds__(256) void phaseE_last(
    const unsigned char* __restrict__ HNb,
    const float* __restrict__ sdstArr,
    const float* __restrict__ sedg,
    const __hip_bfloat16* __restrict__ mb,
    const float* __restrict__ hP,
    const float* __restrict__ ng, const float* __restrict__ nbeta,
    const float* __restrict__ bg, const float* __restrict__ bbeta,
    const int* __restrict__ outrow,
    float* __restrict__ out)
{
    int n = blockIdx.x, j = threadIdx.x;
    int lane = j & 63, wv = j >> 6;
    __shared__ int cntS;
    __shared__ __align__(16) int   eidx[ECAP];
    __shared__ __align__(16) float wh[4][ECAP];
    __shared__ float Zs[4];
    __shared__ float comb[128][2];
    __shared__ float sdv[4];
    __shared__ float red[4];
    if (j < 4) sdv[j] = sdstArr[n * HEADS + j];
    if (j < 64) {
        unsigned b = (j < 32) ? ((const unsigned*)(HNb + (size_t)n * NEB))[j] : 0u;
        int cnt0 = __popc(b);
        int s = cnt0;
        #pragma unroll
        for (int o = 1; o < 64; o <<= 1) {
            int v = __shfl_up(s, o, 64);
            if (j >= o) s += v;
        }
        if (j == 63) cntS = s;
        int off = s - cnt0, eb = j << 5;
        while (b) {
            int i = __ffs(b) - 1; b &= b - 1;
            eidx[off++] = (eb + i) << 9;
        }
    }
    __syncthreads();
    int c = cntS;
    int cP = (c + 7) & ~7;
    for (int i = j; i < c; i += 256) {
        int e = eidx[i] >> 9;
        float4 sg = *(const float4*)&sedg[e * 4];
        float l0 = sdv[0] + sg.x; l0 = l0 > 0.f ? l0 : 0.2f * l0;
        float l1 = sdv[1] + sg.y; l1 = l1 > 0.f ? l1 : 0.2f * l1;
        float l2 = sdv[2] + sg.z; l2 = l2 > 0.f ? l2 : 0.2f * l2;
        float l3 = sdv[3] + sg.w; l3 = l3 > 0.f ? l3 : 0.2f * l3;
        wh[0][i] = __expf(l0); wh[1][i] = __expf(l1);
        wh[2][i] = __expf(l2); wh[3][i] = __expf(l3);
    }
    if (j < 8) {
        int i = c + j;
        if (i < cP) { eidx[i] = 0; wh[0][i] = wh[1][i] = wh[2][i] = wh[3][i] = 0.f; }
    }
    __syncthreads();
    {
        float p = 0.f;
        for (int i = lane; i < c; i += 64) p += wh[wv][i];
        p = waveReduce(p);
        if (lane == 0) Zs[wv] = p;
    }
    __syncthreads();

    int par = j >> 7, p = j & 127, h2 = p >> 5;
    const char* mbb = (const char*)mb;
    int coff = p << 2;
    float a0 = 0.f, b0 = 0.f, a1 = 0.f, b1 = 0.f;
    for (int i = par * 4; i < cP; i += 8) {
        int4   e4 = *(const int4*)&eidx[i];
        float4 w4 = *(const float4*)&wh[h2][i];
        unsigned u0 = *(const unsigned*)(mbb + e4.x + coff);
        unsigned u1 = *(const unsigned*)(mbb + e4.y + coff);
        unsigned u2 = *(const unsigned*)(mbb + e4.z + coff);
        unsigned u3 = *(const unsigned*)(mbb + e4.w + coff);
        a0 += w4.x * bflo(u0); b0 += w4.x * bfhi(u0);
        a1 += w4.y * bflo(u1); b1 += w4.y * bfhi(u1);
        a0 += w4.z * bflo(u2); b0 += w4.z * bfhi(u2);
        a1 += w4.w * bflo(u3); b1 += w4.w * bfhi(u3);
    }
    if (par == 1) { comb[p][0] = a0 + a1; comb[p][1] = b0 + b1; }
    __syncthreads();

    float r0 = 0.f, r1 = 0.f;
    if (par == 0) {
        float o0 = a0 + a1 + comb[p][0];
        float o1 = b0 + b1 + comb[p][1];
        float Zi = 1.f / Zs[h2];
        o0 *= Zi; o1 *= Zi;
        o0 = o0 > 0.f ? o0 : eluNeg(o0);
        o1 = o1 > 0.f ? o1 : eluNeg(o1);
        float2 hr = *(const float2*)&hP[(size_t)n * GNN_DIM + 2 * p];
        r0 = o0 + hr.x; r1 = o1 + hr.y;
    }

    // fused layernorm over this node's 256 columns (par==1 contributes 0)
    float sm = waveReduce(r0 + r1);
    if (lane == 0) red[wv] = sm;
    __syncthreads();
    float mean = (red[0] + red[1] + red[2] + red[3]) * (1.f / GNN_DIM);
    __syncthreads();
    float d0 = r0 - mean, d1 = r1 - mean;
    float sv = (par == 0) ? (d0 * d0 + d1 * d1) : 0.f;
    sv = waveReduce(sv);
    if (lane == 0) red[wv] = sv;
    __syncthreads();
    float var = (red[0] + red[1] + red[2] + red[3]) * (1.f / GNN_DIM);
    if (par == 0) {
        const float* g; const float* bta; size_t outOff;
        if (n < N_PATCH) { g = ng; bta = nbeta; outOff = (size_t)n * GNN_DIM; }
        else {
            int qq = outrow[n - N_PATCH];
            g = bg; bta = bbeta;
            outOff = (size_t)(N_PATCH + qq) * GNN_DIM;
        }
        float is = rsqrtf(var + 1e-5f);
        float2 gv = *(const float2*)&g[2 * p];
        float2 bv = *(const float2*)&bta[2 * p];
        float2 ov; ov.x = d0 * is * gv.x + bv.x; ov.y = d1 * is * gv.y + bv.y;
        *(float2*)&out[outOff + 2 * p] = ov;
    }
}

// ---------------------------------------------------------------------------
extern "C" void kernel_launch(void* const* d_in, const int* in_sizes, int n_in,
                              void* d_out, int out_size, void* d_ws, size_t ws_size,
                              hipStream_t stream) {
    const float* x_nodes   = (const float*)d_in[0];
    const float* readout   = (const float*)d_in[1];
    const int*   node_type = (const int*)d_in[2];
    const int*   edge_type = (const int*)d_in[3];
    const float* Hmat      = (const float*)d_in[4];
    const int*   ro_ids    = (const int*)d_in[5];
    const float* W0        = (const float*)d_in[6];
    const float* W1        = (const float*)d_in[7];
    const float* node_emb  = (const float*)d_in[8];
    const float* a_src     = (const float*)d_in[9];
    const float* a_dst     = (const float*)d_in[10];
    const float* a_edge    = (const float*)d_in[11];
    const float* edge_bias = (const float*)d_in[12];
    const float* node_g    = (const float*)d_in[13];
    const float* node_b    = (const float*)d_in[14];
    const float* bag_g     = (const float*)d_in[15];
    const float* bag_b     = (const float*)d_in[16];

    // Workspace layout (~22.7 MB)
    char* ws = (char*)d_ws;
    size_t off = 0;
    unsigned char* HTb = (unsigned char*)(ws + off); off += (size_t)N_EDGES * NTB;
    unsigned char* HNb = (unsigned char*)(ws + off); off += (size_t)N_TOT * NEB;
    off = (off + 255) & ~(size_t)255;
    float* hP   = (float*)(ws + off); off += (size_t)N_TOT * GNN_DIM * 4;
    __hip_bfloat16* hPb = (__hip_bfloat16*)(ws + off); off += (size_t)N_TOT * GNN_DIM * 2;
    __hip_bfloat16* mb  = (__hip_bfloat16*)(ws + off); off += (size_t)N_EDGES * GNN_DIM * 2;
    __hip_bfloat16* Xb0 = (__hip_bfloat16*)(ws + off); off += (size_t)N_TOT * IN_DIM * 2;
    __hip_bfloat16* Wt0 = (__hip_bfloat16*)(ws + off); off += (size_t)GNN_DIM * IN_DIM * 2;
    __hip_bfloat16* Wt1 = (__hip_bfloat16*)(ws + off); off += (size_t)GNN_DIM * GNN_DIM * 2;
    float* expL = (float*)(ws + off); off += (size_t)N_TOT * 12 * 4;
    float* sdst = (float*)(ws + off); off += (size_t)N_TOT * HEADS * 4;
    float* sedg = (float*)(ws + off); off += (size_t)N_EDGES * HEADS * 4;
    int* outrow = (int*)(ws + off); off += N_TILES * 4;
    __hip_bfloat16* hXb = Xb0;               // alias (Xb0 dead after layer-0 phaseA)

    // ----- fused prep -----
    prep1<<<9001, 256, 0, stream>>>(Hmat, HTb, HNb, W0, Wt0, W1, Wt1,
                                    x_nodes, readout, Xb0, ro_ids, outrow);

    // ----- layer 0 -----
    phaseA_mfma<<<N_TOT / 16, 256, 0, stream>>>(Xb0, Wt0, IN_DIM, IN_DIM + 8,
                                      node_emb, node_type,
                                      a_src, a_dst, edge_bias,
                                      hP, hPb, expL, sdst);
    phaseC_fused<<<N_EDGES, 512, 0, stream>>>(HTb, edge_type, expL, hPb,
                                              a_edge, mb, sedg);
    phaseE<<<N_TOT, 256, 0, stream>>>(HNb, sdst, sedg, mb, hP, hXb);

    // ----- layer 1 -----
    phaseA_mfma<<<N_TOT / 16, 256, 0, stream>>>(hXb, Wt1, GNN_DIM, GNN_DIM + 8,
                                      node_emb + 4 * GNN_DIM, node_type,
                                      a_src + HEADS * DH, a_dst + HEADS * DH,
                                      edge_bias + 12,
                                      hP, hPb, expL, sdst);
    phaseC_fused<<<N_EDGES, 512, 0, stream>>>(HTb, edge_type, expL, hPb,
                                              a_edge + HEADS * DH, mb, sedg);
    phaseE_last<<<N_TOT, 256, 0, stream>>>(HNb, sdst, sedg, mb, hP,
                                           node_g, node_b, bag_g, bag_b, outrow,
                                           (float*)d_out);
}